// Round 9
// baseline (193.327 us; speedup 1.0000x reference)
//
#include <hip/hip_runtime.h>
#include <stdint.h>

typedef unsigned short ushort_t;
typedef __attribute__((ext_vector_type(8))) short short8;
typedef __attribute__((ext_vector_type(4))) short short4v;
typedef __attribute__((ext_vector_type(4))) float f32x4;
typedef __attribute__((ext_vector_type(4))) unsigned uintx4;

#define DEV static __device__ __forceinline__

DEV unsigned short f2bf(float f) {
  unsigned u = __builtin_bit_cast(unsigned, f);
  u += 0x7fffu + ((u >> 16) & 1u);
  return (unsigned short)(u >> 16);
}
DEV float bf2f(unsigned short b) {
  return __builtin_bit_cast(float, (unsigned)b << 16);
}

DEV void gl16(const void* g, void* l) {
  __builtin_amdgcn_global_load_lds(
      (__attribute__((address_space(1))) char*)(unsigned long long)g,
      (__attribute__((address_space(3))) char*)(unsigned)(unsigned long long)l,
      16, 0, 0);
}

DEV f32x4 mfma_bf16(short8 a, short8 b, f32x4 c) {
  return __builtin_amdgcn_mfma_f32_16x16x32_bf16(a, b, c, 0, 0, 0);
}

DEV unsigned cvtpk(float lo, float hi) {
  unsigned r;
  asm("v_cvt_pk_bf16_f32 %0, %1, %2" : "=v"(r) : "v"(lo), "v"(hi));
  return r;
}
DEV void swap_net(unsigned& a, unsigned& b) {
  asm("v_permlane32_swap_b32 %0, %1" : "+v"(a), "+v"(b));
  asm("v_permlane16_swap_b32 %0, %1" : "+v"(a), "+v"(b));
}
DEV float redmax4(float x) {
  unsigned a = __builtin_bit_cast(unsigned, x), b = a;
  asm("v_permlane16_swap_b32 %0, %1" : "+v"(a), "+v"(b));
  float y = fmaxf(__builtin_bit_cast(float, a), __builtin_bit_cast(float, b));
  unsigned c = __builtin_bit_cast(unsigned, y), d = c;
  asm("v_permlane32_swap_b32 %0, %1" : "+v"(c), "+v"(d));
  return fmaxf(__builtin_bit_cast(float, c), __builtin_bit_cast(float, d));
}
DEV float lanebcast(float v, int srclane) {
  return __builtin_bit_cast(float,
      __builtin_amdgcn_ds_bpermute(srclane * 4, __builtin_bit_cast(int, v)));
}

// ---------------- consolidated converts ----------------
__global__ __launch_bounds__(256) void k_cvt_all(
    const float* __restrict__ x, const float* __restrict__ kg,
    const float* __restrict__ Wq, const float* __restrict__ Wk, const float* __restrict__ Wv,
    const float* __restrict__ Wkk, const float* __restrict__ Wkv,
    const float* __restrict__ Wo, const float* __restrict__ Wg,
    ushort_t* __restrict__ xh, ushort_t* __restrict__ kgh,
    ushort_t* __restrict__ WB1, ushort_t* __restrict__ WB2, ushort_t* __restrict__ WB3) {
  const int b = blockIdx.x;
  if (b >= 10752) {
    const int i = (b - 10752) * 256 + threadIdx.x;
    const int r = i >> 8, c = (i & 255) * 4;
    const float4 v = *(const float4*)(Wg + (size_t)r * 2048 + c);
    short4v o;
    o.x = (short)f2bf(v.x); o.y = (short)f2bf(v.y); o.z = (short)f2bf(v.z); o.w = (short)f2bf(v.w);
    *(short4v*)(WB3 + 1048576 + (size_t)r * 1024 + c) = o;
    return;
  }
  const float* src;
  ushort_t* dst;
  int off;
  if (b < 4096)       { src = x;   dst = xh;            off = b; }
  else if (b < 4608)  { src = kg;  dst = kgh;           off = b - 4096; }
  else if (b < 5632)  { src = Wq;  dst = WB1;           off = b - 4608; }
  else if (b < 6656)  { src = Wk;  dst = WB1 + 1048576; off = b - 5632; }
  else if (b < 7680)  { src = Wv;  dst = WB1 + 2097152; off = b - 6656; }
  else if (b < 8704)  { src = Wkk; dst = WB2;           off = b - 7680; }
  else if (b < 9728)  { src = Wkv; dst = WB2 + 1048576; off = b - 8704; }
  else                { src = Wo;  dst = WB3;           off = b - 9728; }
  const int i = off * 1024 + threadIdx.x * 4;
  const float4 v = *(const float4*)(src + i);
  short4v o;
  o.x = (short)f2bf(v.x); o.y = (short)f2bf(v.y); o.z = (short)f2bf(v.z); o.w = (short)f2bf(v.w);
  *(short4v*)(dst + i) = o;
}

__global__ __launch_bounds__(256) void k_kgmean(const float* __restrict__ kg, float* __restrict__ out) {
  const int i = blockIdx.x * 256 + threadIdx.x;
  const int b = i >> 10, d = i & 1023;
  float s = 0.f;
  #pragma unroll 4
  for (int e = 0; e < 256; e++) s += kg[((size_t)b * 256 + e) * 1024 + d];
  out[i] = s * (1.0f / 256.0f);
}

__global__ __launch_bounds__(256) void k_g2(const float* __restrict__ kgm, const float* __restrict__ Wg,
                                            const float* __restrict__ bg, float* __restrict__ g2) {
  const int w = threadIdx.x >> 6, l = threadIdx.x & 63;
  const int idx = blockIdx.x * 4 + w;
  const int b = idx >> 10, n = idx & 1023;
  const float* wr = Wg + (size_t)n * 2048 + 1024;
  const float* mb = kgm + b * 1024;
  float s = 0.f;
  #pragma unroll
  for (int j = 0; j < 16; j++) s += mb[j * 64 + l] * wr[j * 64 + l];
  #pragma unroll
  for (int m = 32; m >= 1; m >>= 1) s += __shfl_xor(s, m);
  if (l == 0) g2[idx] = s + bg[n];
}

// ---------------- 256x256 8-phase GEMM (qkv + kg projections) ----------------
// 512 threads, 8 waves (2M x 4N); per-wave out 128x64; BK=64, 2 K-tiles/iter, 8 iters.
// LDS: 2 slots x (A[256][64] + B[256][64]) = 128KB. Chunk swizzle c' = c ^ (row&7),
// inverse-applied on gl16 global source. vmcnt(4) only at P4/P8.
#define BARm() do { __builtin_amdgcn_s_barrier(); asm volatile("" ::: "memory"); } while (0)

#define RD_A(DST, SBASE, IOFF)                                      \
  _Pragma("unroll")                                                 \
  for (int i = 0; i < 4; i++) {                                     \
    DST[i][0] = *(const short8*)((SBASE) + aoff[(IOFF) + i]);       \
    DST[i][1] = *(const short8*)((SBASE) + (aoff[(IOFF) + i] ^ 64));\
  }
#define RD_B(DST, SBASE, JOFF)                                      \
  _Pragma("unroll")                                                 \
  for (int j = 0; j < 2; j++) {                                     \
    DST[j][0] = *(const short8*)((SBASE) + boff[(JOFF) + j]);       \
    DST[j][1] = *(const short8*)((SBASE) + (boff[(JOFF) + j] ^ 64));\
  }
#define MFMA_QUAD(AF, BF, I0, J0)                                   \
  __builtin_amdgcn_s_setprio(1);                                    \
  _Pragma("unroll")                                                 \
  for (int i = 0; i < 4; i++) {                                     \
    _Pragma("unroll")                                               \
    for (int j = 0; j < 2; j++) {                                   \
      acc[(I0) + i][(J0) + j] = mfma_bf16(AF[i][0], BF[j][0], acc[(I0) + i][(J0) + j]); \
      acc[(I0) + i][(J0) + j] = mfma_bf16(AF[i][1], BF[j][1], acc[(I0) + i][(J0) + j]); \
    }                                                               \
  }                                                                 \
  __builtin_amdgcn_s_setprio(0);

__global__ __launch_bounds__(512, 2) void k_mmqkv(
    const ushort_t* __restrict__ xh, const ushort_t* __restrict__ WB1,
    const ushort_t* __restrict__ kgh, const ushort_t* __restrict__ WB2,
    const float* __restrict__ bq, const float* __restrict__ bk, const float* __restrict__ bv,
    const float* __restrict__ bkk, const float* __restrict__ bkv,
    ushort_t* __restrict__ Qg, ushort_t* __restrict__ Kaug, ushort_t* __restrict__ Vt) {
  __shared__ __align__(16) char SHb[131072];
  const int tid = threadIdx.x;
  const int w = tid >> 6, l = tid & 63;
  const int wr = w >> 2, wc = w & 3;
  const int fr = l & 15, fg = l >> 4;

  int m0, by, iskg = 0;
  const int wg = ((int)blockIdx.x & 7) * 26 + ((int)blockIdx.x >> 3);  // 208 = 8*26
  if (wg < 192) { m0 = (wg / 12) * 256; by = wg % 12; }
  else          { const int k = wg - 192; iskg = 1; by = k & 7; m0 = (k >> 3) * 256; }
  const int n0 = by * 256;
  const ushort_t* A = iskg ? kgh : xh;
  const ushort_t* B = iskg ? WB2 : WB1;

  // staging map: thread covers LDS 16B blocks (j*512+tid); inverse-swizzled source
  const int rIH = tid >> 3;
  const int cc = (tid & 7) ^ (rIH & 7);
  const char* gA = (const char*)A + (size_t)(m0 + rIH) * 2048 + cc * 16;
  const char* gB = (const char*)B + (size_t)(n0 + rIH) * 2048 + cc * 16;

  auto stg = [&](int slot, int ab, int h, int kt) {
    const char* g = (ab ? gB : gA) + (size_t)h * 262144 + kt * 128;
    char* d = SHb + (slot << 16) + ab * 32768 + h * 16384 + tid * 16;
    gl16(g, d);
    gl16(g + 131072, d + 8192);   // +64 rows
  };

  // ds_read offsets: c' = (kk*4+fg) ^ (fr&7); kk=1 => byte ^ 64
  const int swz = (fg ^ (fr & 7)) * 16;
  int aoff[8], boff[4];
  #pragma unroll
  for (int i = 0; i < 8; i++)
    aoff[i] = wr * 16384 + (i * 16 + fr) * 128 + swz;
  #pragma unroll
  for (int j = 0; j < 4; j++)
    boff[j] = 32768 + (wc >> 1) * 16384 + ((wc & 1) * 64 + j * 16 + fr) * 128 + swz;

  f32x4 acc[8][4] = {};

  // prologue: tile0 A+B (slot0), tile1 A (slot1)
  stg(0, 0, 0, 0); stg(0, 0, 1, 0); stg(0, 1, 0, 0); stg(0, 1, 1, 0);
  stg(1, 0, 0, 1); stg(1, 0, 1, 1);
  asm volatile("s_waitcnt vmcnt(4)" ::: "memory");
  BARm();

  const char* S0 = SHb;
  const char* S1 = SHb + 65536;

  for (int it = 0; it < 8; ++it) {
    const int t = 2 * it;
    const bool pre = (t < 14);
    short8 a0[4][2], a1[4][2], b0[2][2], b1[2][2];

    // ---- tile t (slot0) ----
    // P1: read a0(m0-3),b0(n0-1); stage slot1-B0(t+1); MFMA m0-3 x n0-1
    RD_A(a0, S0, 0)
    RD_B(b0, S0, 0)
    stg(1, 1, 0, t + 1);
    BARm();
    MFMA_QUAD(a0, b0, 0, 0)
    BARm();
    // P2: read a1(m4-7); stage slot1-B1(t+1); MFMA m4-7 x n0-1
    RD_A(a1, S0, 4)
    stg(1, 1, 1, t + 1);
    BARm();
    MFMA_QUAD(a1, b0, 4, 0)
    BARm();
    // P3: read b1(n2-3); stage slot0-A0(t+2); MFMA m4-7 x n2-3
    RD_B(b1, S0, 2)
    if (pre) stg(0, 0, 0, t + 2);
    BARm();
    MFMA_QUAD(a1, b1, 4, 2)
    BARm();
    // P4: stage slot0-A1(t+2); MFMA m0-3 x n2-3; vmcnt; bar
    if (pre) stg(0, 0, 1, t + 2);
    BARm();
    MFMA_QUAD(a0, b1, 0, 2)
    if (pre) asm volatile("s_waitcnt vmcnt(4)" ::: "memory");
    else     asm volatile("s_waitcnt vmcnt(0)" ::: "memory");
    BARm();

    // ---- tile t+1 (slot1) ----
    // P5: read a0,b0 (slot1); stage slot0-B0(t+2); MFMA m0-3 x n0-1
    RD_A(a0, S1, 0)
    RD_B(b0, S1, 0)
    if (pre) stg(0, 1, 0, t + 2);
    BARm();
    MFMA_QUAD(a0, b0, 0, 0)
    BARm();
    // P6: read a1; stage slot0-B1(t+2); MFMA m4-7 x n0-1
    RD_A(a1, S1, 4)
    if (pre) stg(0, 1, 1, t + 2);
    BARm();
    MFMA_QUAD(a1, b0, 4, 0)
    BARm();
    // P7: read b1; stage slot1-A0(t+3); MFMA m4-7 x n2-3
    RD_B(b1, S1, 2)
    if (pre) stg(1, 0, 0, t + 3);
    BARm();
    MFMA_QUAD(a1, b1, 4, 2)
    BARm();
    // P8: stage slot1-A1(t+3); MFMA m0-3 x n2-3; vmcnt; bar
    if (pre) stg(1, 0, 1, t + 3);
    BARm();
    MFMA_QUAD(a0, b1, 0, 2)
    if (pre) asm volatile("s_waitcnt vmcnt(4)" ::: "memory");
    else     asm volatile("s_waitcnt vmcnt(0)" ::: "memory");
    BARm();
  }
  __syncthreads();

  // ---------------- epilogues (R6-verified 256^2 geometry) ----------------
  const int sec = iskg ? (by >> 2) + 10 : (by >> 2);
  const int nnbase = (by & 3) * 256;
  const bool isV = (sec == 2 || sec == 11);

  if (isV) {
    // V: transpose via LDS, coalesced Vt writes. SHb reused as [n 256][m 256] bf16.
    ushort_t* SHs = (ushort_t*)SHb;
    const float* bV = iskg ? bkv : bv;
    const int bidx = iskg ? (m0 >> 8) : (m0 >> 11);
    const int colbase = iskg ? (2048 + (m0 & 255)) : (m0 & 2047);
    #pragma unroll
    for (int i = 0; i < 8; i++) {
      #pragma unroll
      for (int j = 0; j < 4; j++) {
        const int nl = wc * 64 + j * 16 + fr;
        const int ml0 = wr * 128 + i * 16 + fg * 4;
        const float bb = bV[nnbase + nl];
        short4v pk;
        #pragma unroll
        for (int r = 0; r < 4; r++) pk[r] = (short)f2bf(acc[i][j][r] + bb);
        *(short4v*)(SHs + nl * 256 + (ml0 ^ ((nl & 7) << 3))) = pk;
      }
    }
    __syncthreads();
    const int nl = tid >> 1, mh = tid & 1;
    const int n = nnbase + nl;
    const int h = n >> 6, d = n & 63;
    ushort_t* dst = Vt + ((size_t)(bidx * 16 + h) * 64 + d) * 2304 + colbase + mh * 128;
    const ushort_t* srcr = SHs + nl * 256;
    #pragma unroll
    for (int k2 = 0; k2 < 16; k2++) {
      const int me = (mh * 128 + k2 * 8) ^ ((nl & 7) << 3);
      *(short8*)(dst + k2 * 8) = *(const short8*)(srcr + me);
    }
    return;
  }

  #pragma unroll
  for (int i = 0; i < 8; i++) {
    #pragma unroll
    for (int j = 0; j < 4; j++) {
      const int nn = nnbase + wc * 64 + j * 16 + fr;
      const int h = nn >> 6, d = nn & 63;
      #pragma unroll
      for (int r = 0; r < 4; r++) {
        const int m = m0 + wr * 128 + i * 16 + fg * 4 + r;
        const float v = acc[i][j][r];
        if (sec == 0) {
          const int b = m >> 11, lq = m & 2047;
          Qg[((size_t)(b * 16 + h) * 2048 + lq) * 64 + d] = f2bf((v + bq[nn]) * 0.18033688f); // 0.125*log2e
        } else if (sec == 1) {
          const int b = m >> 11, lq = m & 2047;
          Kaug[((size_t)(b * 16 + h) * 2304 + lq) * 64 + d] = f2bf(v + bk[nn]);
        } else {  // sec == 10: kg -> Kaug e-part
          const int b = m >> 8, e = m & 255;
          Kaug[((size_t)(b * 16 + h) * 2304 + 2048 + e) * 64 + d] = f2bf(v + bkk[nn]);
        }
      }
    }
  }
}

// ---------------- fused output GEMM + gate + final mix ----------------
__global__ __launch_bounds__(256, 2) void k_mmout(
    const ushort_t* __restrict__ Og, const ushort_t* __restrict__ WB3,
    const float* __restrict__ bo, const float* __restrict__ g2v,
    const float* __restrict__ x, float* __restrict__ y) {
  __shared__ __align__(16) char SHb[61440];   // 3 slots x 20KB (A 4K | Bo 8K | Bg 8K)
  const int tid = threadIdx.x;
  const int w = tid >> 6, l = tid & 63;
  const int wr = w >> 1, wc = w & 1;
  const int fr = l & 15, fg = l >> 4;

  const int wg = ((int)blockIdx.x & 7) * 64 + ((int)blockIdx.x >> 3);   // 512 = 8*64
  const int m0 = (wg >> 3) * 64, n0 = (wg & 7) * 128;

  const int rpA = tid >> 3, uA = (tid & 7) ^ (rpA & 7);
  const char* gAp = (const char*)Og + (size_t)(m0 + 2 * rpA + (uA >> 2)) * 2048 + (uA & 3) * 16;
  int grow[2], gcb[2];
  #pragma unroll
  for (int j = 0; j < 2; j++) {
    const int beta = j * 256 + tid;
    const int rp = beta >> 3;
    const int u = (beta & 7) ^ (rp & 7);
    grow[j] = 2 * rp + (u >> 2);
    gcb[j] = u & 3;
  }
  const char* gBo[2];
  const char* gBg[2];
  #pragma unroll
  for (int j = 0; j < 2; j++) {
    gBo[j] = (const char*)WB3 + (size_t)(n0 + grow[j]) * 2048 + gcb[j] * 16;
    gBg[j] = (const char*)(WB3 + 1048576) + (size_t)(n0 + grow[j]) * 2048 + gcb[j] * 16;
  }

  auto stage = [&](int s, int kt) {
    char* As = SHb + s * 20480;
    const int ko = kt * 64;
    gl16(gAp + ko, As + tid * 16);
    #pragma unroll
    for (int j = 0; j < 2; j++) {
      gl16(gBo[j] + ko, As + 4096 + j * 4096 + tid * 16);
      gl16(gBg[j] + ko, As + 12288 + j * 4096 + tid * 16);
    }
  };

  int aoff[2], boff[4];
  #pragma unroll
  for (int i = 0; i < 2; i++) {
    const int rowa = wr * 32 + i * 16 + fr;
    aoff[i] = (rowa >> 1) * 128 + ((((rowa & 1) << 6) | (fg << 4)) ^ (((rowa >> 1) & 7) << 4));
  }
  #pragma unroll
  for (int j = 0; j < 4; j++) {
    const int rowb = wc * 64 + j * 16 + fr;
    boff[j] = (rowb >> 1) * 128 + ((((rowb & 1) << 6) | (fg << 4)) ^ (((rowb >> 1) & 7) << 4));
  }

  f32x4 ao[2][4] = {};
  f32x4 ag[2][4] = {};

  stage(0, 0);
  stage(1, 1);
  int sc = 0, sn2 = 2;
  for (int kt = 0; kt < 32; kt++) {
    if (kt < 31) asm volatile("s_waitcnt vmcnt(5)" ::: "memory");
    else         asm volatile("s_waitcnt vmcnt(0)" ::: "memory");
    __builtin_amdgcn_s_barrier();
    asm volatile("" ::: "memory");
    if (kt < 30) stage(sn2, kt + 2);
    const char* Ab = SHb + sc * 20480;
    short8 af[2], bof[4], bgf[4];
    #pragma unroll
    for (int i = 0; i < 2; i++) af[i] = *(const short8*)(Ab + aoff[i]);
    #pragma unroll
    for (int j = 0; j < 4; j++) {
      bof[j] = *(const short8*)(Ab + 4096 + boff[j]);
      bgf[j] = *(const short8*)(Ab + 12288 + boff[j]);
    }
    __builtin_amdgcn_s_setprio(1);
    #pragma unroll
    for (int i = 0; i < 2; i++)
      #pragma unroll
      for (int j = 0; j < 4; j++) {
        ao[i][j] = mfma_bf16(af[i], bof[j], ao[i][j]);
        ag[i][j] = mfma_bf16(af[i], bgf[j], ag[i][j]);
      }
    __builtin_amdgcn_s_setprio(0);
    sc++; if (sc == 3) sc = 0;
    sn2++; if (sn2 == 3) sn2 = 0;
  }

  const int bidx = m0 >> 11;
  #pragma unroll
  for (int i = 0; i < 2; i++) {
    #pragma unroll
    for (int j = 0; j < 4; j++) {
      const int nn = n0 + wc * 64 + j * 16 + fr;
      const float bb = bo[nn];
      const float gg = g2v[bidx * 1024 + nn];
      #pragma unroll
      for (int r = 0; r < 4; r++) {
        const int m = m0 + wr * 32 + i * 16 + fg * 4 + r;
        const float co = ao[i][j][r] + bb;
        const float cg = ag[i][j][r] + gg;
        const float gate = 1.0f / (1.0f + __builtin_amdgcn_exp2f(cg * -1.4426950408889634f));
        const float xv = x[(size_t)m * 1024 + nn];
        y[(size_t)m * 1024 + nn] = xv + gate * (co - xv);
      }
    }
  }
}

// ---------------- flash attention (QBLK=64, XCD swizzle, gl16 staging) -------
__global__ __launch_bounds__(256, 4) void k_attn(
    const ushort_t* __restrict__ Qg, const ushort_t* __restrict__ Kg,
    const ushort_t* __restrict__ Vtg, ushort_t* __restrict__ Og) {
  __shared__ __align__(16) ushort_t Ks[2][64 * 64];
  __shared__ __align__(16) ushort_t Vs[2][64 * 64];
  const int tid = threadIdx.x;
  const int w = tid >> 6, l = tid & 63;
  const int fr = l & 15, fg = l >> 4;

  const int id = blockIdx.y * gridDim.x + blockIdx.x;      // 0..1023
  const int bh = (id & 7) * 4 + ((id >> 3) >> 5);
  const int q0 = ((id >> 3) & 31) * 64 + w * 16;

  short8 qf[2];
  {
    const short* qrow = (const short*)(Qg + ((size_t)bh * 2048 + q0 + fr) * 64);
    qf[0] = *(const short8*)(qrow + fg * 8);
    qf[1] = *(const short8*)(qrow + 32 + fg * 8);
  }

  constexpr short ONE = 0x3F80;  // bf16 1.0
  const short8 ones = {ONE, ONE, ONE, ONE, ONE, ONE, ONE, ONE};

  f32x4 o[4] = {};
  f32x4 lacc = {};
  float mrun = -1.0e30f;

  const int rsub = tid >> 3;
  const int cS = ((tid & 7) * 16) ^ ((rsub & 7) << 4);
  const char* kbase = (const char*)(Kg + (size_t)bh * 2304 * 64);
  const char* vbase = (const char*)(Vtg + (size_t)bh * 64 * 2304);

  auto stage = [&](int nb, int tile) {
    #pragma unroll
    for (int j = 0; j < 2; j++) {
      const int row = j * 32 + rsub;
      gl16(kbase + (size_t)(tile * 64 + row) * 128 + cS,
           (char*)&Ks[nb][0] + j * 4096 + tid * 16);
      gl16(vbase + (size_t)row * 4608 + tile * 128 + cS,
           (char*)&Vs[nb][0] + j * 4096 + tid * 16);
    }
  };

  stage(0, 0);

  const int rswz = (fr & 7) << 4;

  for (int mt = 0; mt < 36; mt++) {
    __syncthreads();
    if (mt < 35) stage((mt + 1) & 1, mt + 1);

    const char* Kb = (const char*)&Ks[mt & 1][0];
    const char* Vb = (const char*)&Vs[mt & 1][0];

    f32x4 s[4];
    #pragma unroll
    for (int t = 0; t < 4; t++) {
      const int rb = (t * 16 + fr) * 128 + fg * 16;
      const short8 k0 = *(const short8*)(Kb + (rb ^ rswz));
      const short8 k1 = *(const short8*)(Kb + ((rb + 64) ^ rswz));
      f32x4 z = {};
      z = mfma_bf16(k0, qf[0], z);
      z = mfma_bf16(k1, qf[1], z);
      s[t] = z;
    }

    float m = fmaxf(s[0][0], s[0][1]);
    m = fmaxf(fmaxf(m, s[0][2]), s[0][3]);
    m = fmaxf(fmaxf(m, s[1][0]), s[1][1]);
    m = fmaxf(fmaxf(m, s[1][2]), s[1][3]);
    m = fmaxf(fmaxf(m, s[2][0]), s[2][1]);
    m = fmaxf(fmaxf(m, s[2][2]), s[2][3]);
    m = fmaxf(fmaxf(m, s[3][0]), s[3][1]);
    m = fmaxf(fmaxf(m, s[3][2]), s[3][3]);
    const float mx = redmax4(m);
    if (__any(mx - mrun > 11.5416f)) {
      const float mn = fmaxf(mrun, mx);
      const float al = __builtin_amdgcn_exp2f(mrun - mn);
      mrun = mn;
      float ab[4];
      #pragma unroll
      for (int r = 0; r < 4; r++) ab[r] = lanebcast(al, fg * 4 + r);
      #pragma unroll
      for (int r = 0; r < 4; r++) {
        lacc[r] *= ab[r];
        #pragma unroll
        for (int dt = 0; dt < 4; dt++) o[dt][r] *= ab[r];
      }
    }
    #pragma unroll
    for (int t = 0; t < 4; t++)
      #pragma unroll
      for (int r = 0; r < 4; r++)
        s[t][r] = __builtin_amdgcn_exp2f(s[t][r] - mrun);

    #pragma unroll
    for (int c = 0; c < 2; c++) {
      unsigned a0 = cvtpk(s[2 * c][0], s[2 * c][1]);
      unsigned b0 = cvtpk(s[2 * c + 1][0], s[2 * c + 1][1]);
      unsigned a1 = cvtpk(s[2 * c][2], s[2 * c][3]);
      unsigned b1 = cvtpk(s[2 * c + 1][2], s[2 * c + 1][3]);
      swap_net(a0, b0);
      swap_net(a1, b1);
      uintx4 u;
      u.x = a0; u.y = a1; u.z = b0; u.w = b1;
      const short8 pf = __builtin_bit_cast(short8, u);
      lacc = mfma_bf16(pf, ones, lacc);
      #pragma unroll
      for (int dt = 0; dt < 4; dt++) {
        const int vb2 = ((dt * 16 + fr) * 128) + fg * 16 + c * 64;
        const short8 vf = *(const short8*)(Vb + (vb2 ^ rswz));
        o[dt] = mfma_bf16(pf, vf, o[dt]);
      }
    }
  }

  const int b = bh >> 4, h = bh & 15;
  #pragma unroll
  for (int r = 0; r < 4; r++) {
    const float inv = 1.0f / lacc[r];
    const int q = q0 + fg * 4 + r;
    ushort_t* orow = Og + ((size_t)b * 2048 + q) * 1024 + h * 64;
    #pragma unroll
    for (int dt = 0; dt < 4; dt++) orow[dt * 16 + fr] = f2bf(o[dt][r] * inv);
  }
}

extern "C" void kernel_launch(void* const* d_in, const int* in_sizes, int n_in,
                              void* d_out, int out_size, void* d_ws, size_t ws_size,
                              hipStream_t stream) {
  (void)in_sizes; (void)n_in; (void)out_size; (void)ws_size;
  const float* x   = (const float*)d_in[0];
  const float* kg  = (const float*)d_in[1];
  const float* Wq  = (const float*)d_in[2];
  const float* bq  = (const float*)d_in[3];
  const float* Wk  = (const float*)d_in[4];
  const float* bk  = (const float*)d_in[5];
  const float* Wv  = (const float*)d_in[6];
  const float* bv  = (const float*)d_in[7];
  const float* Wkk = (const float*)d_in[8];
  const float* bkk = (const float*)d_in[9];
  const float* Wkv = (const float*)d_in[10];
  const float* bkv = (const float*)d_in[11];
  const float* Wo  = (const float*)d_in[12];
  const float* bo  = (const float*)d_in[13];
  const float* Wg  = (const float*)d_in[14];
  const float* bg  = (const float*)d_in[15];
  float* y = (float*)d_out;

  char* ws = (char*)d_ws;
  size_t off = 0;
  auto take = [&](size_t bytes) {
    char* p = ws + off;
    off += (bytes + 255) & ~(size_t)255;
    return p;
  };
  ushort_t* xh   = (ushort_t*)take((size_t)4096 * 1024 * 2);
  ushort_t* kgh  = (ushort_t*)take((size_t)512 * 1024 * 2);
  ushort_t* WB1  = (ushort_t*)take((size_t)3072 * 1024 * 2);
  ushort_t* WB2  = (ushort_t*)take((size_t)2048 * 1024 * 2);
  ushort_t* WB3  = (ushort_t*)take((size_t)2048 * 1024 * 2);
  ushort_t* Qg   = (ushort_t*)take((size_t)32 * 2048 * 64 * 2);
  ushort_t* Kaug = (ushort_t*)take((size_t)32 * 2304 * 64 * 2);
  ushort_t* Vt   = (ushort_t*)take((size_t)32 * 2304 * 64 * 2);
  ushort_t* Og   = (ushort_t*)take((size_t)4096 * 1024 * 2);
  float* kgm     = (float*)take(2048 * 4);
  float* g2      = (float*)take(2048 * 4);

  k_cvt_all<<<11776, 256, 0, stream>>>(x, kg, Wq, Wk, Wv, Wkk, Wkv, Wo, Wg,
                                       xh, kgh, WB1, WB2, WB3);
  k_kgmean<<<8, 256, 0, stream>>>(kg, kgm);
  k_g2<<<512, 256, 0, stream>>>(kgm, Wg, bg, g2);

  k_mmqkv<<<208, 512, 0, stream>>>(xh, WB1, kgh, WB2,
                                   bq, bk, bv, bkk, bkv, Qg, Kaug, Vt);
  k_attn<<<dim3(32, 32), 256, 0, stream>>>(Qg, Kaug, Vt, Og);
  k_mmout<<<512, 256, 0, stream>>>(Og, WB3, bo, g2, x, y);
}

// Round 10
// 177.942 us; speedup vs baseline: 1.0865x; 1.0865x over previous
//
#include <hip/hip_runtime.h>
#include <stdint.h>

typedef unsigned short ushort_t;
typedef __attribute__((ext_vector_type(8))) short short8;
typedef __attribute__((ext_vector_type(4))) short short4v;
typedef __attribute__((ext_vector_type(4))) float f32x4;
typedef __attribute__((ext_vector_type(4))) unsigned uintx4;

#define DEV static __device__ __forceinline__

DEV unsigned short f2bf(float f) {
  unsigned u = __builtin_bit_cast(unsigned, f);
  u += 0x7fffu + ((u >> 16) & 1u);
  return (unsigned short)(u >> 16);
}
DEV float bf2f(unsigned short b) {
  return __builtin_bit_cast(float, (unsigned)b << 16);
}

DEV void gl16(const void* g, void* l) {
  __builtin_amdgcn_global_load_lds(
      (__attribute__((address_space(1))) char*)(unsigned long long)g,
      (__attribute__((address_space(3))) char*)(unsigned)(unsigned long long)l,
      16, 0, 0);
}

DEV f32x4 mfma_bf16(short8 a, short8 b, f32x4 c) {
  return __builtin_amdgcn_mfma_f32_16x16x32_bf16(a, b, c, 0, 0, 0);
}

DEV unsigned cvtpk(float lo, float hi) {
  unsigned r;
  asm("v_cvt_pk_bf16_f32 %0, %1, %2" : "=v"(r) : "v"(lo), "v"(hi));
  return r;
}
DEV void swap_net(unsigned& a, unsigned& b) {
  asm("v_permlane32_swap_b32 %0, %1" : "+v"(a), "+v"(b));
  asm("v_permlane16_swap_b32 %0, %1" : "+v"(a), "+v"(b));
}
DEV float redmax4(float x) {
  unsigned a = __builtin_bit_cast(unsigned, x), b = a;
  asm("v_permlane16_swap_b32 %0, %1" : "+v"(a), "+v"(b));
  float y = fmaxf(__builtin_bit_cast(float, a), __builtin_bit_cast(float, b));
  unsigned c = __builtin_bit_cast(unsigned, y), d = c;
  asm("v_permlane32_swap_b32 %0, %1" : "+v"(c), "+v"(d));
  return fmaxf(__builtin_bit_cast(float, c), __builtin_bit_cast(float, d));
}
DEV float lanebcast(float v, int srclane) {
  return __builtin_bit_cast(float,
      __builtin_amdgcn_ds_bpermute(srclane * 4, __builtin_bit_cast(int, v)));
}

// ---------------- consolidated converts (+ kgmean) ----------------
__global__ __launch_bounds__(256) void k_cvt_all(
    const float* __restrict__ x, const float* __restrict__ kg,
    const float* __restrict__ Wq, const float* __restrict__ Wk, const float* __restrict__ Wv,
    const float* __restrict__ Wkk, const float* __restrict__ Wkv,
    const float* __restrict__ Wo, const float* __restrict__ Wg,
    ushort_t* __restrict__ xh, ushort_t* __restrict__ kgh,
    ushort_t* __restrict__ WB1, ushort_t* __restrict__ WB2, ushort_t* __restrict__ WB3,
    float* __restrict__ kgm) {
  const int b = blockIdx.x;
  if (b >= 11776) {
    // kgmean: 8 blocks -> 2048 outputs
    const int i = (b - 11776) * 256 + threadIdx.x;
    const int bb = i >> 10, d = i & 1023;
    float s = 0.f;
    #pragma unroll 4
    for (int e = 0; e < 256; e++) s += kg[((size_t)bb * 256 + e) * 1024 + d];
    kgm[i] = s * (1.0f / 256.0f);
    return;
  }
  if (b >= 10752) {
    const int i = (b - 10752) * 256 + threadIdx.x;
    const int r = i >> 8, c = (i & 255) * 4;
    const float4 v = *(const float4*)(Wg + (size_t)r * 2048 + c);
    short4v o;
    o.x = (short)f2bf(v.x); o.y = (short)f2bf(v.y); o.z = (short)f2bf(v.z); o.w = (short)f2bf(v.w);
    *(short4v*)(WB3 + 1048576 + (size_t)r * 1024 + c) = o;
    return;
  }
  const float* src;
  ushort_t* dst;
  int off;
  if (b < 4096)       { src = x;   dst = xh;            off = b; }
  else if (b < 4608)  { src = kg;  dst = kgh;           off = b - 4096; }
  else if (b < 5632)  { src = Wq;  dst = WB1;           off = b - 4608; }
  else if (b < 6656)  { src = Wk;  dst = WB1 + 1048576; off = b - 5632; }
  else if (b < 7680)  { src = Wv;  dst = WB1 + 2097152; off = b - 6656; }
  else if (b < 8704)  { src = Wkk; dst = WB2;           off = b - 7680; }
  else if (b < 9728)  { src = Wkv; dst = WB2 + 1048576; off = b - 8704; }
  else                { src = Wo;  dst = WB3;           off = b - 9728; }
  const int i = off * 1024 + threadIdx.x * 4;
  const float4 v = *(const float4*)(src + i);
  short4v o;
  o.x = (short)f2bf(v.x); o.y = (short)f2bf(v.y); o.z = (short)f2bf(v.z); o.w = (short)f2bf(v.w);
  *(short4v*)(dst + i) = o;
}

__global__ __launch_bounds__(256) void k_g2(const float* __restrict__ kgm, const float* __restrict__ Wg,
                                            const float* __restrict__ bg, float* __restrict__ g2) {
  const int w = threadIdx.x >> 6, l = threadIdx.x & 63;
  const int idx = blockIdx.x * 4 + w;
  const int b = idx >> 10, n = idx & 1023;
  const float* wr = Wg + (size_t)n * 2048 + 1024;
  const float* mb = kgm + b * 1024;
  float s = 0.f;
  #pragma unroll
  for (int j = 0; j < 16; j++) s += mb[j * 64 + l] * wr[j * 64 + l];
  #pragma unroll
  for (int m = 32; m >= 1; m >>= 1) s += __shfl_xor(s, m);
  if (l == 0) g2[idx] = s + bg[n];
}

// ---------------- 128x128x32 GEMM, 3-slot counted-vmcnt pipeline (qkv+kg) ----------------
__global__ __launch_bounds__(256, 3) void k_mm128(
    const ushort_t* __restrict__ A0, const ushort_t* __restrict__ B0,
    const ushort_t* __restrict__ A1, const ushort_t* __restrict__ B1,
    const float* __restrict__ f0, const float* __restrict__ f1, const float* __restrict__ f2,
    const float* __restrict__ f3, const float* __restrict__ f4,
    ushort_t* __restrict__ o0, ushort_t* __restrict__ o1, ushort_t* __restrict__ o2) {
  __shared__ __align__(16) char SHb[49152];   // 3 slots x 16KB; V-epilogue reuses 32KB
  const int tid = threadIdx.x;
  const int w = tid >> 6, l = tid & 63;
  const int wr = w >> 1, wc = w & 1;
  const int fr = l & 15, fg = l >> 4;

  int m0, n0, iskg = 0;
  {
    const int wg = ((int)blockIdx.x & 7) * 104 + ((int)blockIdx.x >> 3);  // 832 = 8*104
    if (wg < 768) {
      // L2 chunk remap: 8m x 3n chunks (A 2MB + B 0.75MB < 4MB L2 per XCD)
      const int c = wg / 24, r = wg % 24;
      m0 = ((c & 3) * 8 + (r & 7)) * 128;
      n0 = ((c >> 2) * 3 + (r >> 3)) * 128;
    } else {
      const int k = wg - 768; iskg = 1; m0 = (k >> 4) * 128; n0 = (k & 15) * 128;
    }
  }
  const ushort_t* A = iskg ? A1 : A0;
  const ushort_t* B = iskg ? B1 : B0;

  int grow[2], gcb[2];
  #pragma unroll
  for (int j = 0; j < 2; j++) {
    const int beta = j * 256 + tid;
    const int rp = beta >> 3;
    const int u = (beta & 7) ^ (rp & 7);
    grow[j] = 2 * rp + (u >> 2);
    gcb[j] = u & 3;
  }
  const char* gA[2];
  const char* gB[2];
  #pragma unroll
  for (int j = 0; j < 2; j++) {
    gA[j] = (const char*)A + (size_t)(m0 + grow[j]) * 2048 + gcb[j] * 16;
    gB[j] = (const char*)B + (size_t)(n0 + grow[j]) * 2048 + gcb[j] * 16;
  }

  auto stage = [&](int s, int kt) {
    char* As = SHb + s * 16384;
    char* Bs = As + 8192;
    const int ko = kt * 64;
    #pragma unroll
    for (int j = 0; j < 2; j++) {
      gl16(gA[j] + ko, As + j * 4096 + tid * 16);
      gl16(gB[j] + ko, Bs + j * 4096 + tid * 16);
    }
  };

  int aoff[4], boff[4];
  #pragma unroll
  for (int i = 0; i < 4; i++) {
    const int rowa = wr * 64 + i * 16 + fr;
    aoff[i] = (rowa >> 1) * 128 + ((((rowa & 1) << 6) | (fg << 4)) ^ (((rowa >> 1) & 7) << 4));
    const int rowb = wc * 64 + i * 16 + fr;
    boff[i] = (rowb >> 1) * 128 + ((((rowb & 1) << 6) | (fg << 4)) ^ (((rowb >> 1) & 7) << 4));
  }

  f32x4 acc[4][4] = {};

  stage(0, 0);
  stage(1, 1);
  int sc = 0, sn2 = 2;
  for (int kt = 0; kt < 32; kt++) {
    if (kt < 31) asm volatile("s_waitcnt vmcnt(4)" ::: "memory");
    else         asm volatile("s_waitcnt vmcnt(0)" ::: "memory");
    __builtin_amdgcn_s_barrier();
    asm volatile("" ::: "memory");
    if (kt < 30) stage(sn2, kt + 2);
    const char* Ab = SHb + sc * 16384;
    const char* Bb = Ab + 8192;
    short8 af[4], bf[4];
    #pragma unroll
    for (int j = 0; j < 4; j++) bf[j] = *(const short8*)(Bb + boff[j]);
    #pragma unroll
    for (int i = 0; i < 4; i++) af[i] = *(const short8*)(Ab + aoff[i]);
    __builtin_amdgcn_s_setprio(1);
    #pragma unroll
    for (int i = 0; i < 4; i++)
      #pragma unroll
      for (int j = 0; j < 4; j++)
        acc[i][j] = mfma_bf16(af[i], bf[j], acc[i][j]);
    __builtin_amdgcn_s_setprio(0);
    sc++; if (sc == 3) sc = 0;
    sn2++; if (sn2 == 3) sn2 = 0;
  }
  __syncthreads();

  const int sec = n0 >> 10;   // main: 0=Q 1=K 2=V ; kg: 0=Kaug-e 1=Vt-e
  const bool isV = (!iskg && sec == 2) || (iskg && sec == 1);

  if (isV) {
    ushort_t* SHs = (ushort_t*)SHb;
    const float* bV = iskg ? f4 : f2;
    const int bidx = iskg ? (m0 >> 8) : (m0 >> 11);
    const int colbase = iskg ? (2048 + (m0 & 255)) : (m0 & 2047);
    #pragma unroll
    for (int i = 0; i < 4; i++) {
      #pragma unroll
      for (int j = 0; j < 4; j++) {
        const int nl = wc * 64 + j * 16 + fr;
        const int ml0 = wr * 64 + i * 16 + fg * 4;
        const float bb = bV[(n0 & 1023) + nl];
        short4v pk;
        #pragma unroll
        for (int r = 0; r < 4; r++) pk[r] = (short)f2bf(acc[i][j][r] + bb);
        *(short4v*)(SHs + nl * 128 + (ml0 ^ ((nl & 7) << 3))) = pk;
      }
    }
    __syncthreads();
    const int row = tid >> 1, half = tid & 1;
    const int h = ((n0 & 1023) >> 6) + (row >> 6);
    const int d = row & 63;
    ushort_t* dst = o2 + ((size_t)(bidx * 16 + h) * 64 + d) * 2304 + colbase + half * 64;
    const ushort_t* srow2 = SHs + row * 128;
    #pragma unroll
    for (int k2 = 0; k2 < 8; k2++) {
      const int me = (half * 64 + k2 * 8) ^ ((row & 7) << 3);
      *(short8*)(dst + k2 * 8) = *(const short8*)(srow2 + me);
    }
    return;
  }

  #pragma unroll
  for (int i = 0; i < 4; i++) {
    #pragma unroll
    for (int j = 0; j < 4; j++) {
      const int nn = (n0 & 1023) + wc * 64 + j * 16 + fr;
      const int h = nn >> 6, d = nn & 63;
      #pragma unroll
      for (int r = 0; r < 4; r++) {
        const int m = m0 + wr * 64 + i * 16 + fg * 4 + r;
        const float v = acc[i][j][r];
        if (iskg) {
          const int b = m >> 8, e = m & 255;
          o1[((size_t)(b * 16 + h) * 2304 + 2048 + e) * 64 + d] = f2bf(v + f3[nn]);
        } else if (sec == 0) {
          const int b = m >> 11, lq = m & 2047;
          o0[((size_t)(b * 16 + h) * 2048 + lq) * 64 + d] = f2bf((v + f0[nn]) * 0.18033688f); // 0.125*log2e
        } else {
          const int b = m >> 11, lq = m & 2047;
          o1[((size_t)(b * 16 + h) * 2304 + lq) * 64 + d] = f2bf(v + f1[nn]);
        }
      }
    }
  }
}

// ---------------- fused output GEMM + gate + final mix ----------------
__global__ __launch_bounds__(256, 2) void k_mmout(
    const ushort_t* __restrict__ Og, const ushort_t* __restrict__ WB3,
    const float* __restrict__ bo, const float* __restrict__ g2v,
    const float* __restrict__ x, float* __restrict__ y) {
  __shared__ __align__(16) char SHb[61440];   // 3 slots x 20KB (A 4K | Bo 8K | Bg 8K)
  const int tid = threadIdx.x;
  const int w = tid >> 6, l = tid & 63;
  const int wr = w >> 1, wc = w & 1;
  const int fr = l & 15, fg = l >> 4;

  const int wg = ((int)blockIdx.x & 7) * 64 + ((int)blockIdx.x >> 3);   // 512 = 8*64
  const int m0 = (wg >> 3) * 64, n0 = (wg & 7) * 128;

  const int rpA = tid >> 3, uA = (tid & 7) ^ (rpA & 7);
  const char* gAp = (const char*)Og + (size_t)(m0 + 2 * rpA + (uA >> 2)) * 2048 + (uA & 3) * 16;
  int grow[2], gcb[2];
  #pragma unroll
  for (int j = 0; j < 2; j++) {
    const int beta = j * 256 + tid;
    const int rp = beta >> 3;
    const int u = (beta & 7) ^ (rp & 7);
    grow[j] = 2 * rp + (u >> 2);
    gcb[j] = u & 3;
  }
  const char* gBo[2];
  const char* gBg[2];
  #pragma unroll
  for (int j = 0; j < 2; j++) {
    gBo[j] = (const char*)WB3 + (size_t)(n0 + grow[j]) * 2048 + gcb[j] * 16;
    gBg[j] = (const char*)(WB3 + 1048576) + (size_t)(n0 + grow[j]) * 2048 + gcb[j] * 16;
  }

  auto stage = [&](int s, int kt) {
    char* As = SHb + s * 20480;
    const int ko = kt * 64;
    gl16(gAp + ko, As + tid * 16);
    #pragma unroll
    for (int j = 0; j < 2; j++) {
      gl16(gBo[j] + ko, As + 4096 + j * 4096 + tid * 16);
      gl16(gBg[j] + ko, As + 12288 + j * 4096 + tid * 16);
    }
  };

  int aoff[2], boff[4];
  #pragma unroll
  for (int i = 0; i < 2; i++) {
    const int rowa = wr * 32 + i * 16 + fr;
    aoff[i] = (rowa >> 1) * 128 + ((((rowa & 1) << 6) | (fg << 4)) ^ (((rowa >> 1) & 7) << 4));
  }
  #pragma unroll
  for (int j = 0; j < 4; j++) {
    const int rowb = wc * 64 + j * 16 + fr;
    boff[j] = (rowb >> 1) * 128 + ((((rowb & 1) << 6) | (fg << 4)) ^ (((rowb >> 1) & 7) << 4));
  }

  f32x4 ao[2][4] = {};
  f32x4 ag[2][4] = {};

  stage(0, 0);
  stage(1, 1);
  int sc = 0, sn2 = 2;
  for (int kt = 0; kt < 32; kt++) {
    if (kt < 31) asm volatile("s_waitcnt vmcnt(5)" ::: "memory");
    else         asm volatile("s_waitcnt vmcnt(0)" ::: "memory");
    __builtin_amdgcn_s_barrier();
    asm volatile("" ::: "memory");
    if (kt < 30) stage(sn2, kt + 2);
    const char* Ab = SHb + sc * 20480;
    short8 af[2], bof[4], bgf[4];
    #pragma unroll
    for (int i = 0; i < 2; i++) af[i] = *(const short8*)(Ab + aoff[i]);
    #pragma unroll
    for (int j = 0; j < 4; j++) {
      bof[j] = *(const short8*)(Ab + 4096 + boff[j]);
      bgf[j] = *(const short8*)(Ab + 12288 + boff[j]);
    }
    __builtin_amdgcn_s_setprio(1);
    #pragma unroll
    for (int i = 0; i < 2; i++)
      #pragma unroll
      for (int j = 0; j < 4; j++) {
        ao[i][j] = mfma_bf16(af[i], bof[j], ao[i][j]);
        ag[i][j] = mfma_bf16(af[i], bgf[j], ag[i][j]);
      }
    __builtin_amdgcn_s_setprio(0);
    sc++; if (sc == 3) sc = 0;
    sn2++; if (sn2 == 3) sn2 = 0;
  }

  const int bidx = m0 >> 11;
  #pragma unroll
  for (int i = 0; i < 2; i++) {
    #pragma unroll
    for (int j = 0; j < 4; j++) {
      const int nn = n0 + wc * 64 + j * 16 + fr;
      const float bb = bo[nn];
      const float gg = g2v[bidx * 1024 + nn];
      #pragma unroll
      for (int r = 0; r < 4; r++) {
        const int m = m0 + wr * 32 + i * 16 + fg * 4 + r;
        const float co = ao[i][j][r] + bb;
        const float cg = ag[i][j][r] + gg;
        const float gate = 1.0f / (1.0f + __builtin_amdgcn_exp2f(cg * -1.4426950408889634f));
        const float xv = x[(size_t)m * 1024 + nn];
        y[(size_t)m * 1024 + nn] = xv + gate * (co - xv);
      }
    }
  }
}

// ---------------- flash attention (QBLK=64, XCD swizzle, gl16 staging) -------
__global__ __launch_bounds__(256, 4) void k_attn(
    const ushort_t* __restrict__ Qg, const ushort_t* __restrict__ Kg,
    const ushort_t* __restrict__ Vtg, ushort_t* __restrict__ Og) {
  __shared__ __align__(16) ushort_t Ks[2][64 * 64];
  __shared__ __align__(16) ushort_t Vs[2][64 * 64];
  const int tid = threadIdx.x;
  const int w = tid >> 6, l = tid & 63;
  const int fr = l & 15, fg = l >> 4;

  const int id = blockIdx.y * gridDim.x + blockIdx.x;      // 0..1023
  const int bh = (id & 7) * 4 + ((id >> 3) >> 5);
  const int q0 = ((id >> 3) & 31) * 64 + w * 16;

  short8 qf[2];
  {
    const short* qrow = (const short*)(Qg + ((size_t)bh * 2048 + q0 + fr) * 64);
    qf[0] = *(const short8*)(qrow + fg * 8);
    qf[1] = *(const short8*)(qrow + 32 + fg * 8);
  }

  constexpr short ONE = 0x3F80;  // bf16 1.0
  const short8 ones = {ONE, ONE, ONE, ONE, ONE, ONE, ONE, ONE};

  f32x4 o[4] = {};
  f32x4 lacc = {};
  float mrun = -1.0e30f;

  // staging: precomputed per-j base pointers; per-tile uniform byte advance
  const int rsub = tid >> 3;
  const int cS = ((tid & 7) * 16) ^ ((rsub & 7) << 4);
  const char* kb0 = (const char*)(Kg + (size_t)bh * 2304 * 64) + (size_t)rsub * 128 + cS;
  const char* vb0 = (const char*)(Vtg + (size_t)bh * 64 * 2304) + (size_t)rsub * 4608 + cS;
  char* kd0 = (char*)&Ks[0][0] + tid * 16;
  char* vd0 = (char*)&Vs[0][0] + tid * 16;

  auto stage = [&](int nb, int tile) {
    #pragma unroll
    for (int j = 0; j < 2; j++) {
      gl16(kb0 + (size_t)tile * 8192 + j * 4096, kd0 + nb * 8192 + j * 4096);
      gl16(vb0 + j * 147456 + tile * 128,        vd0 + nb * 8192 + j * 4096);
    }
  };

  stage(0, 0);

  const int rswz = (fr & 7) << 4;

  for (int mt = 0; mt < 36; mt++) {
    __syncthreads();
    if (mt < 35) stage((mt + 1) & 1, mt + 1);

    const char* Kb = (const char*)&Ks[mt & 1][0];
    const char* Vb = (const char*)&Vs[mt & 1][0];

    f32x4 s[4];
    #pragma unroll
    for (int t = 0; t < 4; t++) {
      const int rb = (t * 16 + fr) * 128 + fg * 16;
      const short8 k0 = *(const short8*)(Kb + (rb ^ rswz));
      const short8 k1 = *(const short8*)(Kb + ((rb + 64) ^ rswz));
      f32x4 z = {};
      z = mfma_bf16(k0, qf[0], z);
      z = mfma_bf16(k1, qf[1], z);
      s[t] = z;
    }

    float m = fmaxf(s[0][0], s[0][1]);
    m = fmaxf(fmaxf(m, s[0][2]), s[0][3]);
    m = fmaxf(fmaxf(m, s[1][0]), s[1][1]);
    m = fmaxf(fmaxf(m, s[1][2]), s[1][3]);
    m = fmaxf(fmaxf(m, s[2][0]), s[2][1]);
    m = fmaxf(fmaxf(m, s[2][2]), s[2][3]);
    m = fmaxf(fmaxf(m, s[3][0]), s[3][1]);
    m = fmaxf(fmaxf(m, s[3][2]), s[3][3]);
    const float mx = redmax4(m);
    if (__any(mx - mrun > 11.5416f)) {
      const float mn = fmaxf(mrun, mx);
      const float al = __builtin_amdgcn_exp2f(mrun - mn);
      mrun = mn;
      float ab[4];
      #pragma unroll
      for (int r = 0; r < 4; r++) ab[r] = lanebcast(al, fg * 4 + r);
      #pragma unroll
      for (int r = 0; r < 4; r++) {
        lacc[r] *= ab[r];
        #pragma unroll
        for (int dt = 0; dt < 4; dt++) o[dt][r] *= ab[r];
      }
    }
    #pragma unroll
    for (int t = 0; t < 4; t++)
      #pragma unroll
      for (int r = 0; r < 4; r++)
        s[t][r] = __builtin_amdgcn_exp2f(s[t][r] - mrun);

    #pragma unroll
    for (int c = 0; c < 2; c++) {
      unsigned a0 = cvtpk(s[2 * c][0], s[2 * c][1]);
      unsigned b0 = cvtpk(s[2 * c + 1][0], s[2 * c + 1][1]);
      unsigned a1 = cvtpk(s[2 * c][2], s[2 * c][3]);
      unsigned b1 = cvtpk(s[2 * c + 1][2], s[2 * c + 1][3]);
      swap_net(a0, b0);
      swap_net(a1, b1);
      uintx4 u;
      u.x = a0; u.y = a1; u.z = b0; u.w = b1;
      const short8 pf = __builtin_bit_cast(short8, u);
      lacc = mfma_bf16(pf, ones, lacc);
      #pragma unroll
      for (int dt = 0; dt < 4; dt++) {
        const int vb2 = ((dt * 16 + fr) * 128) + fg * 16 + c * 64;
        const short8 vf = *(const short8*)(Vb + (vb2 ^ rswz));
        o[dt] = mfma_bf16(pf, vf, o[dt]);
      }
    }
  }

  const int b = bh >> 4, h = bh & 15;
  #pragma unroll
  for (int r = 0; r < 4; r++) {
    const float inv = 1.0f / lacc[r];
    const int q = q0 + fg * 4 + r;
    ushort_t* orow = Og + ((size_t)b * 2048 + q) * 1024 + h * 64;
    #pragma unroll
    for (int dt = 0; dt < 4; dt++) orow[dt * 16 + fr] = f2bf(o[dt][r] * inv);
  }
}

extern "C" void kernel_launch(void* const* d_in, const int* in_sizes, int n_in,
                              void* d_out, int out_size, void* d_ws, size_t ws_size,
                              hipStream_t stream) {
  (void)in_sizes; (void)n_in; (void)out_size; (void)ws_size;
  const float* x   = (const float*)d_in[0];
  const float* kg  = (const float*)d_in[1];
  const float* Wq  = (const float*)d_in[2];
  const float* bq  = (const float*)d_in[3];
  const float* Wk  = (const float*)d_in[4];
  const float* bk  = (const float*)d_in[5];
  const float* Wv  = (const float*)d_in[6];
  const float* bv  = (const float*)d_in[7];
  const float* Wkk = (const float*)d_in[8];
  const float* bkk = (const float*)d_in[9];
  const float* Wkv = (const float*)d_in[10];
  const float* bkv = (const float*)d_in[11];
  const float* Wo  = (const float*)d_in[12];
  const float* bo  = (const float*)d_in[13];
  const float* Wg  = (const float*)d_in[14];
  const float* bg  = (const float*)d_in[15];
  float* y = (float*)d_out;

  char* ws = (char*)d_ws;
  size_t off = 0;
  auto take = [&](size_t bytes) {
    char* p = ws + off;
    off += (bytes + 255) & ~(size_t)255;
    return p;
  };
  ushort_t* xh   = (ushort_t*)take((size_t)4096 * 1024 * 2);
  ushort_t* kgh  = (ushort_t*)take((size_t)512 * 1024 * 2);
  ushort_t* WB1  = (ushort_t*)take((size_t)3072 * 1024 * 2);
  ushort_t* WB2  = (ushort_t*)take((size_t)2048 * 1024 * 2);
  ushort_t* WB3  = (ushort_t*)take((size_t)2048 * 1024 * 2);
  ushort_t* Qg   = (ushort_t*)take((size_t)32 * 2048 * 64 * 2);
  ushort_t* Kaug = (ushort_t*)take((size_t)32 * 2304 * 64 * 2);
  ushort_t* Vt   = (ushort_t*)take((size_t)32 * 2304 * 64 * 2);
  ushort_t* Og   = (ushort_t*)take((size_t)4096 * 1024 * 2);
  float* kgm     = (float*)take(2048 * 4);
  float* g2      = (float*)take(2048 * 4);

  k_cvt_all<<<11784, 256, 0, stream>>>(x, kg, Wq, Wk, Wv, Wkk, Wkv, Wo, Wg,
                                       xh, kgh, WB1, WB2, WB3, kgm);
  k_g2<<<512, 256, 0, stream>>>(kgm, Wg, bg, g2);

  k_mm128<<<832, 256, 0, stream>>>(xh, WB1, kgh, WB2,
                                   bq, bk, bv, bkk, bkv, Qg, Kaug, Vt);
  k_attn<<<dim3(32, 32), 256, 0, stream>>>(Qg, Kaug, Vt, Og);
  k_mmout<<<512, 256, 0, stream>>>(Og, WB3, bo, g2, x, y);
}

// Round 11
// 175.151 us; speedup vs baseline: 1.1038x; 1.0159x over previous
//
#include <hip/hip_runtime.h>
#include <stdint.h>

typedef unsigned short ushort_t;
typedef __attribute__((ext_vector_type(8))) short short8;
typedef __attribute__((ext_vector_type(4))) short short4v;
typedef __attribute__((ext_vector_type(4))) float f32x4;
typedef __attribute__((ext_vector_type(4))) unsigned uintx4;

#define DEV static __device__ __forceinline__

DEV unsigned short f2bf(float f) {
  unsigned u = __builtin_bit_cast(unsigned, f);
  u += 0x7fffu + ((u >> 16) & 1u);
  return (unsigned short)(u >> 16);
}
DEV float bf2f(unsigned short b) {
  return __builtin_bit_cast(float, (unsigned)b << 16);
}

DEV void gl16(const void* g, void* l) {
  __builtin_amdgcn_global_load_lds(
      (__attribute__((address_space(1))) char*)(unsigned long long)g,
      (__attribute__((address_space(3))) char*)(unsigned)(unsigned long long)l,
      16, 0, 0);
}

DEV f32x4 mfma_bf16(short8 a, short8 b, f32x4 c) {
  return __builtin_amdgcn_mfma_f32_16x16x32_bf16(a, b, c, 0, 0, 0);
}

DEV unsigned cvtpk(float lo, float hi) {
  unsigned r;
  asm("v_cvt_pk_bf16_f32 %0, %1, %2" : "=v"(r) : "v"(lo), "v"(hi));
  return r;
}
DEV void swap_net(unsigned& a, unsigned& b) {
  asm("v_permlane32_swap_b32 %0, %1" : "+v"(a), "+v"(b));
  asm("v_permlane16_swap_b32 %0, %1" : "+v"(a), "+v"(b));
}
DEV float redmax4(float x) {
  unsigned a = __builtin_bit_cast(unsigned, x), b = a;
  asm("v_permlane16_swap_b32 %0, %1" : "+v"(a), "+v"(b));
  float y = fmaxf(__builtin_bit_cast(float, a), __builtin_bit_cast(float, b));
  unsigned c = __builtin_bit_cast(unsigned, y), d = c;
  asm("v_permlane32_swap_b32 %0, %1" : "+v"(c), "+v"(d));
  return fmaxf(__builtin_bit_cast(float, c), __builtin_bit_cast(float, d));
}
DEV float lanebcast(float v, int srclane) {
  return __builtin_bit_cast(float,
      __builtin_amdgcn_ds_bpermute(srclane * 4, __builtin_bit_cast(int, v)));
}

// ---------------- consolidated converts (+ kgmean) ----------------
__global__ __launch_bounds__(256) void k_cvt_all(
    const float* __restrict__ x, const float* __restrict__ kg,
    const float* __restrict__ Wq, const float* __restrict__ Wk, const float* __restrict__ Wv,
    const float* __restrict__ Wkk, const float* __restrict__ Wkv,
    const float* __restrict__ Wo, const float* __restrict__ Wg,
    ushort_t* __restrict__ xh, ushort_t* __restrict__ kgh,
    ushort_t* __restrict__ WB1, ushort_t* __restrict__ WB2, ushort_t* __restrict__ WB3,
    float* __restrict__ kgm) {
  const int b = blockIdx.x;
  if (b >= 11776) {
    // kgmean: 8 blocks -> 2048 outputs
    const int i = (b - 11776) * 256 + threadIdx.x;
    const int bb = i >> 10, d = i & 1023;
    float s = 0.f;
    #pragma unroll 4
    for (int e = 0; e < 256; e++) s += kg[((size_t)bb * 256 + e) * 1024 + d];
    kgm[i] = s * (1.0f / 256.0f);
    return;
  }
  if (b >= 10752) {
    const int i = (b - 10752) * 256 + threadIdx.x;
    const int r = i >> 8, c = (i & 255) * 4;
    const float4 v = *(const float4*)(Wg + (size_t)r * 2048 + c);
    short4v o;
    o.x = (short)f2bf(v.x); o.y = (short)f2bf(v.y); o.z = (short)f2bf(v.z); o.w = (short)f2bf(v.w);
    *(short4v*)(WB3 + 1048576 + (size_t)r * 1024 + c) = o;
    return;
  }
  const float* src;
  ushort_t* dst;
  int off;
  if (b < 4096)       { src = x;   dst = xh;            off = b; }
  else if (b < 4608)  { src = kg;  dst = kgh;           off = b - 4096; }
  else if (b < 5632)  { src = Wq;  dst = WB1;           off = b - 4608; }
  else if (b < 6656)  { src = Wk;  dst = WB1 + 1048576; off = b - 5632; }
  else if (b < 7680)  { src = Wv;  dst = WB1 + 2097152; off = b - 6656; }
  else if (b < 8704)  { src = Wkk; dst = WB2;           off = b - 7680; }
  else if (b < 9728)  { src = Wkv; dst = WB2 + 1048576; off = b - 8704; }
  else                { src = Wo;  dst = WB3;           off = b - 9728; }
  const int i = off * 1024 + threadIdx.x * 4;
  const float4 v = *(const float4*)(src + i);
  short4v o;
  o.x = (short)f2bf(v.x); o.y = (short)f2bf(v.y); o.z = (short)f2bf(v.z); o.w = (short)f2bf(v.w);
  *(short4v*)(dst + i) = o;
}

__global__ __launch_bounds__(256) void k_g2(const float* __restrict__ kgm, const float* __restrict__ Wg,
                                            const float* __restrict__ bg, float* __restrict__ g2) {
  const int w = threadIdx.x >> 6, l = threadIdx.x & 63;
  const int idx = blockIdx.x * 4 + w;
  const int b = idx >> 10, n = idx & 1023;
  const float* wr = Wg + (size_t)n * 2048 + 1024;
  const float* mb = kgm + b * 1024;
  float s = 0.f;
  #pragma unroll
  for (int j = 0; j < 16; j++) s += mb[j * 64 + l] * wr[j * 64 + l];
  #pragma unroll
  for (int m = 32; m >= 1; m >>= 1) s += __shfl_xor(s, m);
  if (l == 0) g2[idx] = s + bg[n];
}

// ---------------- 128x128x32 GEMM, 3-slot counted-vmcnt pipeline (qkv+kg) ----------------
__global__ __launch_bounds__(256, 3) void k_mm128(
    const ushort_t* __restrict__ A0, const ushort_t* __restrict__ B0,
    const ushort_t* __restrict__ A1, const ushort_t* __restrict__ B1,
    const float* __restrict__ f0, const float* __restrict__ f1, const float* __restrict__ f2,
    const float* __restrict__ f3, const float* __restrict__ f4,
    ushort_t* __restrict__ o0, ushort_t* __restrict__ o1, ushort_t* __restrict__ o2) {
  __shared__ __align__(16) char SHb[49152];   // 3 slots x 16KB; V-epilogue reuses 32KB
  const int tid = threadIdx.x;
  const int w = tid >> 6, l = tid & 63;
  const int wr = w >> 1, wc = w & 1;
  const int fr = l & 15, fg = l >> 4;

  int m0, n0, iskg = 0;
  {
    const int wg = ((int)blockIdx.x & 7) * 104 + ((int)blockIdx.x >> 3);  // 832 = 8*104
    if (wg < 768) { m0 = (wg / 24) * 128; n0 = (wg % 24) * 128; }
    else          { const int k = wg - 768; iskg = 1; m0 = (k >> 4) * 128; n0 = (k & 15) * 128; }
  }
  const ushort_t* A = iskg ? A1 : A0;
  const ushort_t* B = iskg ? B1 : B0;

  int grow[2], gcb[2];
  #pragma unroll
  for (int j = 0; j < 2; j++) {
    const int beta = j * 256 + tid;
    const int rp = beta >> 3;
    const int u = (beta & 7) ^ (rp & 7);
    grow[j] = 2 * rp + (u >> 2);
    gcb[j] = u & 3;
  }
  const char* gA[2];
  const char* gB[2];
  #pragma unroll
  for (int j = 0; j < 2; j++) {
    gA[j] = (const char*)A + (size_t)(m0 + grow[j]) * 2048 + gcb[j] * 16;
    gB[j] = (const char*)B + (size_t)(n0 + grow[j]) * 2048 + gcb[j] * 16;
  }

  auto stage = [&](int s, int kt) {
    char* As = SHb + s * 16384;
    char* Bs = As + 8192;
    const int ko = kt * 64;
    #pragma unroll
    for (int j = 0; j < 2; j++) {
      gl16(gA[j] + ko, As + j * 4096 + tid * 16);
      gl16(gB[j] + ko, Bs + j * 4096 + tid * 16);
    }
  };

  int aoff[4], boff[4];
  #pragma unroll
  for (int i = 0; i < 4; i++) {
    const int rowa = wr * 64 + i * 16 + fr;
    aoff[i] = (rowa >> 1) * 128 + ((((rowa & 1) << 6) | (fg << 4)) ^ (((rowa >> 1) & 7) << 4));
    const int rowb = wc * 64 + i * 16 + fr;
    boff[i] = (rowb >> 1) * 128 + ((((rowb & 1) << 6) | (fg << 4)) ^ (((rowb >> 1) & 7) << 4));
  }

  f32x4 acc[4][4] = {};

  stage(0, 0);
  stage(1, 1);
  int sc = 0, sn2 = 2;
  for (int kt = 0; kt < 32; kt++) {
    if (kt < 31) asm volatile("s_waitcnt vmcnt(4)" ::: "memory");
    else         asm volatile("s_waitcnt vmcnt(0)" ::: "memory");
    __builtin_amdgcn_s_barrier();
    asm volatile("" ::: "memory");
    if (kt < 30) stage(sn2, kt + 2);
    const char* Ab = SHb + sc * 16384;
    const char* Bb = Ab + 8192;
    short8 af[4], bf[4];
    #pragma unroll
    for (int j = 0; j < 4; j++) bf[j] = *(const short8*)(Bb + boff[j]);
    #pragma unroll
    for (int i = 0; i < 4; i++) af[i] = *(const short8*)(Ab + aoff[i]);
    __builtin_amdgcn_s_setprio(1);
    #pragma unroll
    for (int i = 0; i < 4; i++)
      #pragma unroll
      for (int j = 0; j < 4; j++)
        acc[i][j] = mfma_bf16(af[i], bf[j], acc[i][j]);
    __builtin_amdgcn_s_setprio(0);
    sc++; if (sc == 3) sc = 0;
    sn2++; if (sn2 == 3) sn2 = 0;
  }
  __syncthreads();

  const int sec = n0 >> 10;   // main: 0=Q 1=K 2=V ; kg: 0=Kaug-e 1=Vt-e
  const bool isV = (!iskg && sec == 2) || (iskg && sec == 1);

  if (isV) {
    ushort_t* SHs = (ushort_t*)SHb;
    const float* bV = iskg ? f4 : f2;
    const int bidx = iskg ? (m0 >> 8) : (m0 >> 11);
    const int colbase = iskg ? (2048 + (m0 & 255)) : (m0 & 2047);
    #pragma unroll
    for (int i = 0; i < 4; i++) {
      #pragma unroll
      for (int j = 0; j < 4; j++) {
        const int nl = wc * 64 + j * 16 + fr;
        const int ml0 = wr * 64 + i * 16 + fg * 4;
        const float bb = bV[(n0 & 1023) + nl];
        short4v pk;
        #pragma unroll
        for (int r = 0; r < 4; r++) pk[r] = (short)f2bf(acc[i][j][r] + bb);
        *(short4v*)(SHs + nl * 128 + (ml0 ^ ((nl & 7) << 3))) = pk;
      }
    }
    __syncthreads();
    const int row = tid >> 1, half = tid & 1;
    const int h = ((n0 & 1023) >> 6) + (row >> 6);
    const int d = row & 63;
    ushort_t* dst = o2 + ((size_t)(bidx * 16 + h) * 64 + d) * 2304 + colbase + half * 64;
    const ushort_t* srow2 = SHs + row * 128;
    #pragma unroll
    for (int k2 = 0; k2 < 8; k2++) {
      const int me = (half * 64 + k2 * 8) ^ ((row & 7) << 3);
      *(short8*)(dst + k2 * 8) = *(const short8*)(srow2 + me);
    }
    return;
  }

  #pragma unroll
  for (int i = 0; i < 4; i++) {
    #pragma unroll
    for (int j = 0; j < 4; j++) {
      const int nn = (n0 & 1023) + wc * 64 + j * 16 + fr;
      const int h = nn >> 6, d = nn & 63;
      #pragma unroll
      for (int r = 0; r < 4; r++) {
        const int m = m0 + wr * 64 + i * 16 + fg * 4 + r;
        const float v = acc[i][j][r];
        if (iskg) {
          const int b = m >> 8, e = m & 255;
          o1[((size_t)(b * 16 + h) * 2304 + 2048 + e) * 64 + d] = f2bf(v + f3[nn]);
        } else if (sec == 0) {
          const int b = m >> 11, lq = m & 2047;
          o0[((size_t)(b * 16 + h) * 2048 + lq) * 64 + d] = f2bf((v + f0[nn]) * 0.18033688f); // 0.125*log2e
        } else {
          const int b = m >> 11, lq = m & 2047;
          o1[((size_t)(b * 16 + h) * 2304 + lq) * 64 + d] = f2bf(v + f1[nn]);
        }
      }
    }
  }
}

// ---------------- fused output GEMM + gate + final mix ----------------
__global__ __launch_bounds__(256, 2) void k_mmout(
    const ushort_t* __restrict__ Og, const ushort_t* __restrict__ WB3,
    const float* __restrict__ bo, const float* __restrict__ g2v,
    const float* __restrict__ x, float* __restrict__ y) {
  __shared__ __align__(16) char SHb[61440];   // 3 slots x 20KB (A 4K | Bo 8K | Bg 8K)
  const int tid = threadIdx.x;
  const int w = tid >> 6, l = tid & 63;
  const int wr = w >> 1, wc = w & 1;
  const int fr = l & 15, fg = l >> 4;

  const int wg = ((int)blockIdx.x & 7) * 64 + ((int)blockIdx.x >> 3);   // 512 = 8*64
  const int m0 = (wg >> 3) * 64, n0 = (wg & 7) * 128;

  const int rpA = tid >> 3, uA = (tid & 7) ^ (rpA & 7);
  const char* gAp = (const char*)Og + (size_t)(m0 + 2 * rpA + (uA >> 2)) * 2048 + (uA & 3) * 16;
  int grow[2], gcb[2];
  #pragma unroll
  for (int j = 0; j < 2; j++) {
    const int beta = j * 256 + tid;
    const int rp = beta >> 3;
    const int u = (beta & 7) ^ (rp & 7);
    grow[j] = 2 * rp + (u >> 2);
    gcb[j] = u & 3;
  }
  const char* gBo[2];
  const char* gBg[2];
  #pragma unroll
  for (int j = 0; j < 2; j++) {
    gBo[j] = (const char*)WB3 + (size_t)(n0 + grow[j]) * 2048 + gcb[j] * 16;
    gBg[j] = (const char*)(WB3 + 1048576) + (size_t)(n0 + grow[j]) * 2048 + gcb[j] * 16;
  }

  auto stage = [&](int s, int kt) {
    char* As = SHb + s * 20480;
    const int ko = kt * 64;
    gl16(gAp + ko, As + tid * 16);
    #pragma unroll
    for (int j = 0; j < 2; j++) {
      gl16(gBo[j] + ko, As + 4096 + j * 4096 + tid * 16);
      gl16(gBg[j] + ko, As + 12288 + j * 4096 + tid * 16);
    }
  };

  int aoff[2], boff[4];
  #pragma unroll
  for (int i = 0; i < 2; i++) {
    const int rowa = wr * 32 + i * 16 + fr;
    aoff[i] = (rowa >> 1) * 128 + ((((rowa & 1) << 6) | (fg << 4)) ^ (((rowa >> 1) & 7) << 4));
  }
  #pragma unroll
  for (int j = 0; j < 4; j++) {
    const int rowb = wc * 64 + j * 16 + fr;
    boff[j] = (rowb >> 1) * 128 + ((((rowb & 1) << 6) | (fg << 4)) ^ (((rowb >> 1) & 7) << 4));
  }

  f32x4 ao[2][4] = {};
  f32x4 ag[2][4] = {};

  stage(0, 0);
  stage(1, 1);
  int sc = 0, sn2 = 2;
  for (int kt = 0; kt < 32; kt++) {
    if (kt < 31) asm volatile("s_waitcnt vmcnt(5)" ::: "memory");
    else         asm volatile("s_waitcnt vmcnt(0)" ::: "memory");
    __builtin_amdgcn_s_barrier();
    asm volatile("" ::: "memory");
    if (kt < 30) stage(sn2, kt + 2);
    const char* Ab = SHb + sc * 20480;
    short8 af[2], bof[4], bgf[4];
    #pragma unroll
    for (int i = 0; i < 2; i++) af[i] = *(const short8*)(Ab + aoff[i]);
    #pragma unroll
    for (int j = 0; j < 4; j++) {
      bof[j] = *(const short8*)(Ab + 4096 + boff[j]);
      bgf[j] = *(const short8*)(Ab + 12288 + boff[j]);
    }
    __builtin_amdgcn_s_setprio(1);
    #pragma unroll
    for (int i = 0; i < 2; i++)
      #pragma unroll
      for (int j = 0; j < 4; j++) {
        ao[i][j] = mfma_bf16(af[i], bof[j], ao[i][j]);
        ag[i][j] = mfma_bf16(af[i], bgf[j], ag[i][j]);
      }
    __builtin_amdgcn_s_setprio(0);
    sc++; if (sc == 3) sc = 0;
    sn2++; if (sn2 == 3) sn2 = 0;
  }

  const int bidx = m0 >> 11;
  #pragma unroll
  for (int i = 0; i < 2; i++) {
    #pragma unroll
    for (int j = 0; j < 4; j++) {
      const int nn = n0 + wc * 64 + j * 16 + fr;
      const float bb = bo[nn];
      const float gg = g2v[bidx * 1024 + nn];
      #pragma unroll
      for (int r = 0; r < 4; r++) {
        const int m = m0 + wr * 32 + i * 16 + fg * 4 + r;
        const float co = ao[i][j][r] + bb;
        const float cg = ag[i][j][r] + gg;
        const float gate = 1.0f / (1.0f + __builtin_amdgcn_exp2f(cg * -1.4426950408889634f));
        const float xv = x[(size_t)m * 1024 + nn];
        y[(size_t)m * 1024 + nn] = xv + gate * (co - xv);
      }
    }
  }
}

// ---------------- flash attention (QBLK=64, XCD swizzle, gl16 staging) -------
__global__ __launch_bounds__(256, 4) void k_attn(
    const ushort_t* __restrict__ Qg, const ushort_t* __restrict__ Kg,
    const ushort_t* __restrict__ Vtg, ushort_t* __restrict__ Og) {
  __shared__ __align__(16) ushort_t Ks[2][64 * 64];
  __shared__ __align__(16) ushort_t Vs[2][64 * 64];
  const int tid = threadIdx.x;
  const int w = tid >> 6, l = tid & 63;
  const int fr = l & 15, fg = l >> 4;

  const int id = blockIdx.y * gridDim.x + blockIdx.x;      // 0..1023
  const int bh = (id & 7) * 4 + ((id >> 3) >> 5);
  const int q0 = ((id >> 3) & 31) * 64 + w * 16;

  short8 qf[2];
  {
    const short* qrow = (const short*)(Qg + ((size_t)bh * 2048 + q0 + fr) * 64);
    qf[0] = *(const short8*)(qrow + fg * 8);
    qf[1] = *(const short8*)(qrow + 32 + fg * 8);
  }

  constexpr short ONE = 0x3F80;  // bf16 1.0
  const short8 ones = {ONE, ONE, ONE, ONE, ONE, ONE, ONE, ONE};

  f32x4 o[4] = {};
  f32x4 lacc = {};
  float mrun = -1.0e30f;

  // staging: precomputed per-j base pointers; per-tile uniform byte advance
  const int rsub = tid >> 3;
  const int cS = ((tid & 7) * 16) ^ ((rsub & 7) << 4);
  const char* kb0 = (const char*)(Kg + (size_t)bh * 2304 * 64) + (size_t)rsub * 128 + cS;
  const char* vb0 = (const char*)(Vtg + (size_t)bh * 64 * 2304) + (size_t)rsub * 4608 + cS;
  char* kd0 = (char*)&Ks[0][0] + tid * 16;
  char* vd0 = (char*)&Vs[0][0] + tid * 16;

  auto stage = [&](int nb, int tile) {
    #pragma unroll
    for (int j = 0; j < 2; j++) {
      gl16(kb0 + (size_t)tile * 8192 + j * 4096, kd0 + nb * 8192 + j * 4096);
      gl16(vb0 + j * 147456 + tile * 128,        vd0 + nb * 8192 + j * 4096);
    }
  };

  stage(0, 0);

  const int rswz = (fr & 7) << 4;

  for (int mt = 0; mt < 36; mt++) {
    __syncthreads();
    if (mt < 35) stage((mt + 1) & 1, mt + 1);

    const char* Kb = (const char*)&Ks[mt & 1][0];
    const char* Vb = (const char*)&Vs[mt & 1][0];

    f32x4 s[4];
    #pragma unroll
    for (int t = 0; t < 4; t++) {
      const int rb = (t * 16 + fr) * 128 + fg * 16;
      const short8 k0 = *(const short8*)(Kb + (rb ^ rswz));
      const short8 k1 = *(const short8*)(Kb + ((rb + 64) ^ rswz));
      f32x4 z = {};
      z = mfma_bf16(k0, qf[0], z);
      z = mfma_bf16(k1, qf[1], z);
      s[t] = z;
    }

    float m = fmaxf(s[0][0], s[0][1]);
    m = fmaxf(fmaxf(m, s[0][2]), s[0][3]);
    m = fmaxf(fmaxf(m, s[1][0]), s[1][1]);
    m = fmaxf(fmaxf(m, s[1][2]), s[1][3]);
    m = fmaxf(fmaxf(m, s[2][0]), s[2][1]);
    m = fmaxf(fmaxf(m, s[2][2]), s[2][3]);
    m = fmaxf(fmaxf(m, s[3][0]), s[3][1]);
    m = fmaxf(fmaxf(m, s[3][2]), s[3][3]);
    const float mx = redmax4(m);
    if (__any(mx - mrun > 11.5416f)) {
      const float mn = fmaxf(mrun, mx);
      const float al = __builtin_amdgcn_exp2f(mrun - mn);
      mrun = mn;
      float ab[4];
      #pragma unroll
      for (int r = 0; r < 4; r++) ab[r] = lanebcast(al, fg * 4 + r);
      #pragma unroll
      for (int r = 0; r < 4; r++) {
        lacc[r] *= ab[r];
        #pragma unroll
        for (int dt = 0; dt < 4; dt++) o[dt][r] *= ab[r];
      }
    }
    #pragma unroll
    for (int t = 0; t < 4; t++)
      #pragma unroll
      for (int r = 0; r < 4; r++)
        s[t][r] = __builtin_amdgcn_exp2f(s[t][r] - mrun);

    #pragma unroll
    for (int c = 0; c < 2; c++) {
      unsigned a0 = cvtpk(s[2 * c][0], s[2 * c][1]);
      unsigned b0 = cvtpk(s[2 * c + 1][0], s[2 * c + 1][1]);
      unsigned a1 = cvtpk(s[2 * c][2], s[2 * c][3]);
      unsigned b1 = cvtpk(s[2 * c + 1][2], s[2 * c + 1][3]);
      swap_net(a0, b0);
      swap_net(a1, b1);
      uintx4 u;
      u.x = a0; u.y = a1; u.z = b0; u.w = b1;
      const short8 pf = __builtin_bit_cast(short8, u);
      lacc = mfma_bf16(pf, ones, lacc);
      #pragma unroll
      for (int dt = 0; dt < 4; dt++) {
        const int vb2 = ((dt * 16 + fr) * 128) + fg * 16 + c * 64;
        const short8 vf = *(const short8*)(Vb + (vb2 ^ rswz));
        o[dt] = mfma_bf16(pf, vf, o[dt]);
      }
    }
  }

  const int b = bh >> 4, h = bh & 15;
  #pragma unroll
  for (int r = 0; r < 4; r++) {
    const float inv = 1.0f / lacc[r];
    const int q = q0 + fg * 4 + r;
    ushort_t* orow = Og + ((size_t)b * 2048 + q) * 1024 + h * 64;
    #pragma unroll
    for (int dt = 0; dt < 4; dt++) orow[dt * 16 + fr] = f2bf(o[dt][r] * inv);
  }
}

extern "C" void kernel_launch(void* const* d_in, const int* in_sizes, int n_in,
                              void* d_out, int out_size, void* d_ws, size_t ws_size,
                              hipStream_t stream) {
  (void)in_sizes; (void)n_in; (void)out_size; (void)ws_size;
  const float* x   = (const float*)d_in[0];
  const float* kg  = (const float*)d_in[1];
  const float* Wq  = (const float*)d_in[2];
  const float* bq  = (const float*)d_in[3];
  const float* Wk  = (const float*)d_in[4];
  const float* bk  = (const float*)d_in[5];
  const float* Wv  = (const float*)d_in[6];
  const float* bv  = (const float*)d_in[7];
  const float* Wkk = (const float*)d_in[8];
  const float* bkk = (const float*)d_in[9];
  const float* Wkv = (const float*)d_in[10];
  const float* bkv = (const float*)d_in[11];
  const float* Wo  = (const float*)d_in[12];
  const float* bo  = (const float*)d_in[13];
  const float* Wg  = (const float*)d_in[14];
  const float* bg  = (const float*)d_in[15];
  float* y = (float*)d_out;

  char* ws = (char*)d_ws;
  size_t off = 0;
  auto take = [&](size_t bytes) {
    char* p = ws + off;
    off += (bytes + 255) & ~(size_t)255;
    return p;
  };
  ushort_t* xh   = (ushort_t*)take((size_t)4096 * 1024 * 2);
  ushort_t* kgh  = (ushort_t*)take((size_t)512 * 1024 * 2);
  ushort_t* WB1  = (ushort_t*)take((size_t)3072 * 1024 * 2);
  ushort_t* WB2  = (ushort_t*)take((size_t)2048 * 1024 * 2);
  ushort_t* WB3  = (ushort_t*)take((size_t)2048 * 1024 * 2);
  ushort_t* Qg   = (ushort_t*)take((size_t)32 * 2048 * 64 * 2);
  ushort_t* Kaug = (ushort_t*)take((size_t)32 * 2304 * 64 * 2);
  ushort_t* Vt   = (ushort_t*)take((size_t)32 * 2304 * 64 * 2);
  ushort_t* Og   = (ushort_t*)take((size_t)4096 * 1024 * 2);
  float* kgm     = (float*)take(2048 * 4);
  float* g2      = (float*)take(2048 * 4);

  k_cvt_all<<<11784, 256, 0, stream>>>(x, kg, Wq, Wk, Wv, Wkk, Wkv, Wo, Wg,
                                       xh, kgh, WB1, WB2, WB3, kgm);
  k_g2<<<512, 256, 0, stream>>>(kgm, Wg, bg, g2);

  k_mm128<<<832, 256, 0, stream>>>(xh, WB1, kgh, WB2,
                                   bq, bk, bv, bkk, bkv, Qg, Kaug, Vt);
  k_attn<<<dim3(32, 32), 256, 0, stream>>>(Qg, Kaug, Vt, Og);
  k_mmout<<<512, 256, 0, stream>>>(Og, WB3, bo, g2, x, y);
}

// Round 12
// 174.928 us; speedup vs baseline: 1.1052x; 1.0013x over previous
//
#include <hip/hip_runtime.h>
#include <stdint.h>

typedef unsigned short ushort_t;
typedef __attribute__((ext_vector_type(8))) short short8;
typedef __attribute__((ext_vector_type(4))) short short4v;
typedef __attribute__((ext_vector_type(4))) float f32x4;
typedef __attribute__((ext_vector_type(4))) unsigned uintx4;

#define DEV static __device__ __forceinline__

DEV unsigned short f2bf(float f) {
  unsigned u = __builtin_bit_cast(unsigned, f);
  u += 0x7fffu + ((u >> 16) & 1u);
  return (unsigned short)(u >> 16);
}
DEV float bf2f(unsigned short b) {
  return __builtin_bit_cast(float, (unsigned)b << 16);
}

DEV void gl16(const void* g, void* l) {
  __builtin_amdgcn_global_load_lds(
      (__attribute__((address_space(1))) char*)(unsigned long long)g,
      (__attribute__((address_space(3))) char*)(unsigned)(unsigned long long)l,
      16, 0, 0);
}

DEV f32x4 mfma_bf16(short8 a, short8 b, f32x4 c) {
  return __builtin_amdgcn_mfma_f32_16x16x32_bf16(a, b, c, 0, 0, 0);
}

DEV unsigned cvtpk(float lo, float hi) {
  unsigned r;
  asm("v_cvt_pk_bf16_f32 %0, %1, %2" : "=v"(r) : "v"(lo), "v"(hi));
  return r;
}
DEV void swap_net(unsigned& a, unsigned& b) {
  asm("v_permlane32_swap_b32 %0, %1" : "+v"(a), "+v"(b));
  asm("v_permlane16_swap_b32 %0, %1" : "+v"(a), "+v"(b));
}
DEV float redmax4(float x) {
  unsigned a = __builtin_bit_cast(unsigned, x), b = a;
  asm("v_permlane16_swap_b32 %0, %1" : "+v"(a), "+v"(b));
  float y = fmaxf(__builtin_bit_cast(float, a), __builtin_bit_cast(float, b));
  unsigned c = __builtin_bit_cast(unsigned, y), d = c;
  asm("v_permlane32_swap_b32 %0, %1" : "+v"(c), "+v"(d));
  return fmaxf(__builtin_bit_cast(float, c), __builtin_bit_cast(float, d));
}
DEV float lanebcast(float v, int srclane) {
  return __builtin_bit_cast(float,
      __builtin_amdgcn_ds_bpermute(srclane * 4, __builtin_bit_cast(int, v)));
}

// ---------------- consolidated converts (+ kgmean) ----------------
__global__ __launch_bounds__(256) void k_cvt_all(
    const float* __restrict__ x, const float* __restrict__ kg,
    const float* __restrict__ Wq, const float* __restrict__ Wk, const float* __restrict__ Wv,
    const float* __restrict__ Wkk, const float* __restrict__ Wkv,
    const float* __restrict__ Wo, const float* __restrict__ Wg,
    ushort_t* __restrict__ xh, ushort_t* __restrict__ kgh,
    ushort_t* __restrict__ WB1, ushort_t* __restrict__ WB2, ushort_t* __restrict__ WB3,
    float* __restrict__ kgm) {
  const int b = blockIdx.x;
  if (b >= 11776) {
    // kgmean: 8 blocks -> 2048 outputs
    const int i = (b - 11776) * 256 + threadIdx.x;
    const int bb = i >> 10, d = i & 1023;
    float s = 0.f;
    #pragma unroll 4
    for (int e = 0; e < 256; e++) s += kg[((size_t)bb * 256 + e) * 1024 + d];
    kgm[i] = s * (1.0f / 256.0f);
    return;
  }
  if (b >= 10752) {
    const int i = (b - 10752) * 256 + threadIdx.x;
    const int r = i >> 8, c = (i & 255) * 4;
    const float4 v = *(const float4*)(Wg + (size_t)r * 2048 + c);
    short4v o;
    o.x = (short)f2bf(v.x); o.y = (short)f2bf(v.y); o.z = (short)f2bf(v.z); o.w = (short)f2bf(v.w);
    *(short4v*)(WB3 + 1048576 + (size_t)r * 1024 + c) = o;
    return;
  }
  const float* src;
  ushort_t* dst;
  int off;
  if (b < 4096)       { src = x;   dst = xh;            off = b; }
  else if (b < 4608)  { src = kg;  dst = kgh;           off = b - 4096; }
  else if (b < 5632)  { src = Wq;  dst = WB1;           off = b - 4608; }
  else if (b < 6656)  { src = Wk;  dst = WB1 + 1048576; off = b - 5632; }
  else if (b < 7680)  { src = Wv;  dst = WB1 + 2097152; off = b - 6656; }
  else if (b < 8704)  { src = Wkk; dst = WB2;           off = b - 7680; }
  else if (b < 9728)  { src = Wkv; dst = WB2 + 1048576; off = b - 8704; }
  else                { src = Wo;  dst = WB3;           off = b - 9728; }
  const int i = off * 1024 + threadIdx.x * 4;
  const float4 v = *(const float4*)(src + i);
  short4v o;
  o.x = (short)f2bf(v.x); o.y = (short)f2bf(v.y); o.z = (short)f2bf(v.z); o.w = (short)f2bf(v.w);
  *(short4v*)(dst + i) = o;
}

__global__ __launch_bounds__(256) void k_g2(const float* __restrict__ kgm, const float* __restrict__ Wg,
                                            const float* __restrict__ bg, float* __restrict__ g2) {
  const int w = threadIdx.x >> 6, l = threadIdx.x & 63;
  const int idx = blockIdx.x * 4 + w;
  const int b = idx >> 10, n = idx & 1023;
  const float* wr = Wg + (size_t)n * 2048 + 1024;
  const float* mb = kgm + b * 1024;
  float s = 0.f;
  #pragma unroll
  for (int j = 0; j < 16; j++) s += mb[j * 64 + l] * wr[j * 64 + l];
  #pragma unroll
  for (int m = 32; m >= 1; m >>= 1) s += __shfl_xor(s, m);
  if (l == 0) g2[idx] = s + bg[n];
}

// ---------------- 128x128x32 GEMM, 3-slot counted-vmcnt pipeline (qkv+kg) ----------------
__global__ __launch_bounds__(256, 3) void k_mm128(
    const ushort_t* __restrict__ A0, const ushort_t* __restrict__ B0,
    const ushort_t* __restrict__ A1, const ushort_t* __restrict__ B1,
    const float* __restrict__ f0, const float* __restrict__ f1, const float* __restrict__ f2,
    const float* __restrict__ f3, const float* __restrict__ f4,
    ushort_t* __restrict__ o0, ushort_t* __restrict__ o1, ushort_t* __restrict__ o2) {
  __shared__ __align__(16) char SHb[49152];   // 3 slots x 16KB; V-epilogue reuses 32KB
  const int tid = threadIdx.x;
  const int w = tid >> 6, l = tid & 63;
  const int wr = w >> 1, wc = w & 1;
  const int fr = l & 15, fg = l >> 4;

  int m0, n0, iskg = 0;
  {
    const int wg = ((int)blockIdx.x & 7) * 104 + ((int)blockIdx.x >> 3);  // 832 = 8*104
    if (wg < 768) { m0 = (wg / 24) * 128; n0 = (wg % 24) * 128; }
    else          { const int k = wg - 768; iskg = 1; m0 = (k >> 4) * 128; n0 = (k & 15) * 128; }
  }
  const ushort_t* A = iskg ? A1 : A0;
  const ushort_t* B = iskg ? B1 : B0;

  int grow[2], gcb[2];
  #pragma unroll
  for (int j = 0; j < 2; j++) {
    const int beta = j * 256 + tid;
    const int rp = beta >> 3;
    const int u = (beta & 7) ^ (rp & 7);
    grow[j] = 2 * rp + (u >> 2);
    gcb[j] = u & 3;
  }
  const char* gA[2];
  const char* gB[2];
  #pragma unroll
  for (int j = 0; j < 2; j++) {
    gA[j] = (const char*)A + (size_t)(m0 + grow[j]) * 2048 + gcb[j] * 16;
    gB[j] = (const char*)B + (size_t)(n0 + grow[j]) * 2048 + gcb[j] * 16;
  }

  auto stage = [&](int s, int kt) {
    char* As = SHb + s * 16384;
    char* Bs = As + 8192;
    const int ko = kt * 64;
    #pragma unroll
    for (int j = 0; j < 2; j++) {
      gl16(gA[j] + ko, As + j * 4096 + tid * 16);
      gl16(gB[j] + ko, Bs + j * 4096 + tid * 16);
    }
  };

  int aoff[4], boff[4];
  #pragma unroll
  for (int i = 0; i < 4; i++) {
    const int rowa = wr * 64 + i * 16 + fr;
    aoff[i] = (rowa >> 1) * 128 + ((((rowa & 1) << 6) | (fg << 4)) ^ (((rowa >> 1) & 7) << 4));
    const int rowb = wc * 64 + i * 16 + fr;
    boff[i] = (rowb >> 1) * 128 + ((((rowb & 1) << 6) | (fg << 4)) ^ (((rowb >> 1) & 7) << 4));
  }

  f32x4 acc[4][4] = {};

  stage(0, 0);
  stage(1, 1);
  int sc = 0, sn2 = 2;
  for (int kt = 0; kt < 32; kt++) {
    if (kt < 31) asm volatile("s_waitcnt vmcnt(4)" ::: "memory");
    else         asm volatile("s_waitcnt vmcnt(0)" ::: "memory");
    __builtin_amdgcn_s_barrier();
    asm volatile("" ::: "memory");
    if (kt < 30) stage(sn2, kt + 2);
    const char* Ab = SHb + sc * 16384;
    const char* Bb = Ab + 8192;
    short8 af[4], bf[4];
    #pragma unroll
    for (int j = 0; j < 4; j++) bf[j] = *(const short8*)(Bb + boff[j]);
    #pragma unroll
    for (int i = 0; i < 4; i++) af[i] = *(const short8*)(Ab + aoff[i]);
    __builtin_amdgcn_s_setprio(1);
    #pragma unroll
    for (int i = 0; i < 4; i++)
      #pragma unroll
      for (int j = 0; j < 4; j++)
        acc[i][j] = mfma_bf16(af[i], bf[j], acc[i][j]);
    __builtin_amdgcn_s_setprio(0);
    sc++; if (sc == 3) sc = 0;
    sn2++; if (sn2 == 3) sn2 = 0;
  }
  __syncthreads();

  const int sec = n0 >> 10;   // main: 0=Q 1=K 2=V ; kg: 0=Kaug-e 1=Vt-e
  const bool isV = (!iskg && sec == 2) || (iskg && sec == 1);

  if (isV) {
    ushort_t* SHs = (ushort_t*)SHb;
    const float* bV = iskg ? f4 : f2;
    const int bidx = iskg ? (m0 >> 8) : (m0 >> 11);
    const int colbase = iskg ? (2048 + (m0 & 255)) : (m0 & 2047);
    #pragma unroll
    for (int i = 0; i < 4; i++) {
      #pragma unroll
      for (int j = 0; j < 4; j++) {
        const int nl = wc * 64 + j * 16 + fr;
        const int ml0 = wr * 64 + i * 16 + fg * 4;
        const float bb = bV[(n0 & 1023) + nl];
        short4v pk;
        #pragma unroll
        for (int r = 0; r < 4; r++) pk[r] = (short)f2bf(acc[i][j][r] + bb);
        *(short4v*)(SHs + nl * 128 + (ml0 ^ ((nl & 7) << 3))) = pk;
      }
    }
    __syncthreads();
    const int row = tid >> 1, half = tid & 1;
    const int h = ((n0 & 1023) >> 6) + (row >> 6);
    const int d = row & 63;
    ushort_t* dst = o2 + ((size_t)(bidx * 16 + h) * 64 + d) * 2304 + colbase + half * 64;
    const ushort_t* srow2 = SHs + row * 128;
    #pragma unroll
    for (int k2 = 0; k2 < 8; k2++) {
      const int me = (half * 64 + k2 * 8) ^ ((row & 7) << 3);
      *(short8*)(dst + k2 * 8) = *(const short8*)(srow2 + me);
    }
    return;
  }

  #pragma unroll
  for (int i = 0; i < 4; i++) {
    #pragma unroll
    for (int j = 0; j < 4; j++) {
      const int nn = (n0 & 1023) + wc * 64 + j * 16 + fr;
      const int h = nn >> 6, d = nn & 63;
      #pragma unroll
      for (int r = 0; r < 4; r++) {
        const int m = m0 + wr * 64 + i * 16 + fg * 4 + r;
        const float v = acc[i][j][r];
        if (iskg) {
          const int b = m >> 8, e = m & 255;
          o1[((size_t)(b * 16 + h) * 2304 + 2048 + e) * 64 + d] = f2bf(v + f3[nn]);
        } else if (sec == 0) {
          const int b = m >> 11, lq = m & 2047;
          o0[((size_t)(b * 16 + h) * 2048 + lq) * 64 + d] = f2bf((v + f0[nn]) * 0.18033688f); // 0.125*log2e
        } else {
          const int b = m >> 11, lq = m & 2047;
          o1[((size_t)(b * 16 + h) * 2304 + lq) * 64 + d] = f2bf(v + f1[nn]);
        }
      }
    }
  }
}

// ---------------- fused output GEMM + gate + final mix ----------------
__global__ __launch_bounds__(256, 2) void k_mmout(
    const ushort_t* __restrict__ Og, const ushort_t* __restrict__ WB3,
    const float* __restrict__ bo, const float* __restrict__ g2v,
    const float* __restrict__ x, float* __restrict__ y) {
  __shared__ __align__(16) char SHb[61440];   // 3 slots x 20KB (A 4K | Bo 8K | Bg 8K)
  const int tid = threadIdx.x;
  const int w = tid >> 6, l = tid & 63;
  const int wr = w >> 1, wc = w & 1;
  const int fr = l & 15, fg = l >> 4;

  const int wg = ((int)blockIdx.x & 7) * 64 + ((int)blockIdx.x >> 3);   // 512 = 8*64
  const int m0 = (wg >> 3) * 64, n0 = (wg & 7) * 128;

  const int rpA = tid >> 3, uA = (tid & 7) ^ (rpA & 7);
  const char* gAp = (const char*)Og + (size_t)(m0 + 2 * rpA + (uA >> 2)) * 2048 + (uA & 3) * 16;
  int grow[2], gcb[2];
  #pragma unroll
  for (int j = 0; j < 2; j++) {
    const int beta = j * 256 + tid;
    const int rp = beta >> 3;
    const int u = (beta & 7) ^ (rp & 7);
    grow[j] = 2 * rp + (u >> 2);
    gcb[j] = u & 3;
  }
  const char* gBo[2];
  const char* gBg[2];
  #pragma unroll
  for (int j = 0; j < 2; j++) {
    gBo[j] = (const char*)WB3 + (size_t)(n0 + grow[j]) * 2048 + gcb[j] * 16;
    gBg[j] = (const char*)(WB3 + 1048576) + (size_t)(n0 + grow[j]) * 2048 + gcb[j] * 16;
  }

  auto stage = [&](int s, int kt) {
    char* As = SHb + s * 20480;
    const int ko = kt * 64;
    gl16(gAp + ko, As + tid * 16);
    #pragma unroll
    for (int j = 0; j < 2; j++) {
      gl16(gBo[j] + ko, As + 4096 + j * 4096 + tid * 16);
      gl16(gBg[j] + ko, As + 12288 + j * 4096 + tid * 16);
    }
  };

  int aoff[2], boff[4];
  #pragma unroll
  for (int i = 0; i < 2; i++) {
    const int rowa = wr * 32 + i * 16 + fr;
    aoff[i] = (rowa >> 1) * 128 + ((((rowa & 1) << 6) | (fg << 4)) ^ (((rowa >> 1) & 7) << 4));
  }
  #pragma unroll
  for (int j = 0; j < 4; j++) {
    const int rowb = wc * 64 + j * 16 + fr;
    boff[j] = (rowb >> 1) * 128 + ((((rowb & 1) << 6) | (fg << 4)) ^ (((rowb >> 1) & 7) << 4));
  }

  f32x4 ao[2][4] = {};
  f32x4 ag[2][4] = {};

  stage(0, 0);
  stage(1, 1);
  int sc = 0, sn2 = 2;
  for (int kt = 0; kt < 32; kt++) {
    if (kt < 31) asm volatile("s_waitcnt vmcnt(5)" ::: "memory");
    else         asm volatile("s_waitcnt vmcnt(0)" ::: "memory");
    __builtin_amdgcn_s_barrier();
    asm volatile("" ::: "memory");
    if (kt < 30) stage(sn2, kt + 2);
    const char* Ab = SHb + sc * 20480;
    short8 af[2], bof[4], bgf[4];
    #pragma unroll
    for (int i = 0; i < 2; i++) af[i] = *(const short8*)(Ab + aoff[i]);
    #pragma unroll
    for (int j = 0; j < 4; j++) {
      bof[j] = *(const short8*)(Ab + 4096 + boff[j]);
      bgf[j] = *(const short8*)(Ab + 12288 + boff[j]);
    }
    __builtin_amdgcn_s_setprio(1);
    #pragma unroll
    for (int i = 0; i < 2; i++)
      #pragma unroll
      for (int j = 0; j < 4; j++) {
        ao[i][j] = mfma_bf16(af[i], bof[j], ao[i][j]);
        ag[i][j] = mfma_bf16(af[i], bgf[j], ag[i][j]);
      }
    __builtin_amdgcn_s_setprio(0);
    sc++; if (sc == 3) sc = 0;
    sn2++; if (sn2 == 3) sn2 = 0;
  }

  const int bidx = m0 >> 11;
  #pragma unroll
  for (int i = 0; i < 2; i++) {
    #pragma unroll
    for (int j = 0; j < 4; j++) {
      const int nn = n0 + wc * 64 + j * 16 + fr;
      const float bb = bo[nn];
      const float gg = g2v[bidx * 1024 + nn];
      #pragma unroll
      for (int r = 0; r < 4; r++) {
        const int m = m0 + wr * 32 + i * 16 + fg * 4 + r;
        const float co = ao[i][j][r] + bb;
        const float cg = ag[i][j][r] + gg;
        const float gate = 1.0f / (1.0f + __builtin_amdgcn_exp2f(cg * -1.4426950408889634f));
        const float xv = x[(size_t)m * 1024 + nn];
        y[(size_t)m * 1024 + nn] = xv + gate * (co - xv);
      }
    }
  }
}

// ---------------- flash attention (QBLK=64, XCD swizzle, z-seeded softmax) -------
__global__ __launch_bounds__(256, 4) void k_attn(
    const ushort_t* __restrict__ Qg, const ushort_t* __restrict__ Kg,
    const ushort_t* __restrict__ Vtg, ushort_t* __restrict__ Og) {
  __shared__ __align__(16) ushort_t Ks[2][64 * 64];
  __shared__ __align__(16) ushort_t Vs[2][64 * 64];
  const int tid = threadIdx.x;
  const int w = tid >> 6, l = tid & 63;
  const int fr = l & 15, fg = l >> 4;

  const int id = blockIdx.y * gridDim.x + blockIdx.x;      // 0..1023
  const int bh = (id & 7) * 4 + ((id >> 3) >> 5);
  const int q0 = ((id >> 3) & 31) * 64 + w * 16;

  short8 qf[2];
  {
    const short* qrow = (const short*)(Qg + ((size_t)bh * 2048 + q0 + fr) * 64);
    qf[0] = *(const short8*)(qrow + fg * 8);
    qf[1] = *(const short8*)(qrow + 32 + fg * 8);
  }

  constexpr short ONE = 0x3F80;  // bf16 1.0
  const short8 ones = {ONE, ONE, ONE, ONE, ONE, ONE, ONE, ONE};

  f32x4 o[4] = {};
  f32x4 lacc = {};
  // shifted-domain online softmax: zs = -mrun (seeded into the QK^T accumulator,
  // eliminating the per-element subtract). mrun starts at 0; scores here are
  // ~|3| << 11.54 threshold, so the rescale branch is cold (kept for safety).
  f32x4 zs = {};

  // staging: precomputed per-j base pointers; per-tile uniform byte advance
  const int rsub = tid >> 3;
  const int cS = ((tid & 7) * 16) ^ ((rsub & 7) << 4);
  const char* kb0 = (const char*)(Kg + (size_t)bh * 2304 * 64) + (size_t)rsub * 128 + cS;
  const char* vb0 = (const char*)(Vtg + (size_t)bh * 64 * 2304) + (size_t)rsub * 4608 + cS;
  char* kd0 = (char*)&Ks[0][0] + tid * 16;
  char* vd0 = (char*)&Vs[0][0] + tid * 16;

  auto stage = [&](int nb, int tile) {
    #pragma unroll
    for (int j = 0; j < 2; j++) {
      gl16(kb0 + (size_t)tile * 8192 + j * 4096, kd0 + nb * 8192 + j * 4096);
      gl16(vb0 + j * 147456 + tile * 128,        vd0 + nb * 8192 + j * 4096);
    }
  };

  stage(0, 0);

  const int rswz = (fr & 7) << 4;

  for (int mt = 0; mt < 36; mt++) {
    __syncthreads();
    if (mt < 35) stage((mt + 1) & 1, mt + 1);

    const char* Kb = (const char*)&Ks[mt & 1][0];
    const char* Vb = (const char*)&Vs[mt & 1][0];

    // swapped QK^T, accumulator pre-seeded with -mrun: s = q.k - mrun directly
    f32x4 s[4];
    #pragma unroll
    for (int t = 0; t < 4; t++) {
      const int rb = (t * 16 + fr) * 128 + fg * 16;
      const short8 k0 = *(const short8*)(Kb + (rb ^ rswz));
      const short8 k1 = *(const short8*)(Kb + ((rb + 64) ^ rswz));
      f32x4 z = zs;
      z = mfma_bf16(k0, qf[0], z);
      z = mfma_bf16(k1, qf[1], z);
      s[t] = z;
    }

    float m = fmaxf(s[0][0], s[0][1]);
    m = fmaxf(fmaxf(m, s[0][2]), s[0][3]);
    m = fmaxf(fmaxf(m, s[1][0]), s[1][1]);
    m = fmaxf(fmaxf(m, s[1][2]), s[1][3]);
    m = fmaxf(fmaxf(m, s[2][0]), s[2][1]);
    m = fmaxf(fmaxf(m, s[2][2]), s[2][3]);
    m = fmaxf(fmaxf(m, s[3][0]), s[3][1]);
    m = fmaxf(fmaxf(m, s[3][2]), s[3][3]);
    const float mx = redmax4(m);
    if (__any(mx > 11.5416f)) {   // cold path: grow the shift, rescale state
      const float d = fmaxf(mx, 0.f);
      const float al = __builtin_amdgcn_exp2f(-d);
      #pragma unroll
      for (int r = 0; r < 4; r++) zs[r] -= d;
      float ab[4];
      #pragma unroll
      for (int r = 0; r < 4; r++) ab[r] = lanebcast(al, fg * 4 + r);
      #pragma unroll
      for (int r = 0; r < 4; r++) {
        lacc[r] *= ab[r];
        #pragma unroll
        for (int dt = 0; dt < 4; dt++) o[dt][r] *= ab[r];
      }
      #pragma unroll
      for (int t = 0; t < 4; t++)
        #pragma unroll
        for (int r = 0; r < 4; r++)
          s[t][r] = __builtin_amdgcn_exp2f(s[t][r] - d);
    } else {                      // hot path: no subtract at all
      #pragma unroll
      for (int t = 0; t < 4; t++)
        #pragma unroll
        for (int r = 0; r < 4; r++)
          s[t][r] = __builtin_amdgcn_exp2f(s[t][r]);
    }

    #pragma unroll
    for (int c = 0; c < 2; c++) {
      unsigned a0 = cvtpk(s[2 * c][0], s[2 * c][1]);
      unsigned b0 = cvtpk(s[2 * c + 1][0], s[2 * c + 1][1]);
      unsigned a1 = cvtpk(s[2 * c][2], s[2 * c][3]);
      unsigned b1 = cvtpk(s[2 * c + 1][2], s[2 * c + 1][3]);
      swap_net(a0, b0);
      swap_net(a1, b1);
      uintx4 u;
      u.x = a0; u.y = a1; u.z = b0; u.w = b1;
      const short8 pf = __builtin_bit_cast(short8, u);
      lacc = mfma_bf16(pf, ones, lacc);
      #pragma unroll
      for (int dt = 0; dt < 4; dt++) {
        const int vb2 = ((dt * 16 + fr) * 128) + fg * 16 + c * 64;
        const short8 vf = *(const short8*)(Vb + (vb2 ^ rswz));
        o[dt] = mfma_bf16(pf, vf, o[dt]);
      }
    }
  }

  const int b = bh >> 4, h = bh & 15;
  #pragma unroll
  for (int r = 0; r < 4; r++) {
    const float inv = 1.0f / lacc[r];
    const int q = q0 + fg * 4 + r;
    ushort_t* orow = Og + ((size_t)b * 2048 + q) * 1024 + h * 64;
    #pragma unroll
    for (int dt = 0; dt < 4; dt++) orow[dt * 16 + fr] = f2bf(o[dt][r] * inv);
  }
}

extern "C" void kernel_launch(void* const* d_in, const int* in_sizes, int n_in,
                              void* d_out, int out_size, void* d_ws, size_t ws_size,
                              hipStream_t stream) {
  (void)in_sizes; (void)n_in; (void)out_size; (void)ws_size;
  const float* x   = (const float*)d_in[0];
  const float* kg  = (const float*)d_in[1];
  const float* Wq  = (const float*)d_in[2];
  const float* bq  = (const float*)d_in[3];
  const float* Wk  = (const float*)d_in[4];
  const float* bk  = (const float*)d_in[5];
  const float* Wv  = (const float*)d_in[6];
  const float* bv  = (const float*)d_in[7];
  const float* Wkk = (const float*)d_in[8];
  const float* bkk = (const float*)d_in[9];
  const float* Wkv = (const float*)d_in[10];
  const float* bkv = (const float*)d_in[11];
  const float* Wo  = (const float*)d_in[12];
  const float* bo  = (const float*)d_in[13];
  const float* Wg  = (const float*)d_in[14];
  const float* bg  = (const float*)d_in[15];
  float* y = (float*)d_out;

  char* ws = (char*)d_ws;
  size_t off = 0;
  auto take = [&](size_t bytes) {
    char* p = ws + off;
    off += (bytes + 255) & ~(size_t)255;
    return p;
  };
  ushort_t* xh   = (ushort_t*)take((size_t)4096 * 1024 * 2);
  ushort_t* kgh  = (ushort_t*)take((size_t)512 * 1024 * 2);
  ushort_t* WB1  = (ushort_t*)take((size_t)3072 * 1024 * 2);
  ushort_t* WB2  = (ushort_t*)take((size_t)2048 * 1024 * 2);
  ushort_t* WB3  = (ushort_t*)take((size_t)2048 * 1024 * 2);
  ushort_t* Qg   = (ushort_t*)take((size_t)32 * 2048 * 64 * 2);
  ushort_t* Kaug = (ushort_t*)take((size_t)32 * 2304 * 64 * 2);
  ushort_t* Vt   = (ushort_t*)take((size_t)32 * 2304 * 64 * 2);
  ushort_t* Og   = (ushort_t*)take((size_t)4096 * 1024 * 2);
  float* kgm     = (float*)take(2048 * 4);
  float* g2      = (float*)take(2048 * 4);

  k_cvt_all<<<11784, 256, 0, stream>>>(x, kg, Wq, Wk, Wv, Wkk, Wkv, Wo, Wg,
                                       xh, kgh, WB1, WB2, WB3, kgm);
  k_g2<<<512, 256, 0, stream>>>(kgm, Wg, bg, g2);

  k_mm128<<<832, 256, 0, stream>>>(xh, WB1, kgh, WB2,
                                   bq, bk, bv, bkk, bkv, Qg, Kaug, Vt);
  k_attn<<<dim3(32, 32), 256, 0, stream>>>(Qg, Kaug, Vt, Og);
  k_mmout<<<512, 256, 0, stream>>>(Og, WB3, bo, g2, x, y);
}

// Round 13
// 168.735 us; speedup vs baseline: 1.1457x; 1.0367x over previous
//
#include <hip/hip_runtime.h>
#include <stdint.h>

typedef unsigned short ushort_t;
typedef __attribute__((ext_vector_type(8))) short short8;
typedef __attribute__((ext_vector_type(4))) short short4v;
typedef __attribute__((ext_vector_type(4))) float f32x4;
typedef __attribute__((ext_vector_type(4))) unsigned uintx4;

#define DEV static __device__ __forceinline__

DEV unsigned short f2bf(float f) {
  unsigned u = __builtin_bit_cast(unsigned, f);
  u += 0x7fffu + ((u >> 16) & 1u);
  return (unsigned short)(u >> 16);
}
DEV float bf2f(unsigned short b) {
  return __builtin_bit_cast(float, (unsigned)b << 16);
}

DEV void gl16(const void* g, void* l) {
  __builtin_amdgcn_global_load_lds(
      (__attribute__((address_space(1))) char*)(unsigned long long)g,
      (__attribute__((address_space(3))) char*)(unsigned)(unsigned long long)l,
      16, 0, 0);
}

DEV f32x4 mfma_bf16(short8 a, short8 b, f32x4 c) {
  return __builtin_amdgcn_mfma_f32_16x16x32_bf16(a, b, c, 0, 0, 0);
}

DEV unsigned cvtpk(float lo, float hi) {
  unsigned r;
  asm("v_cvt_pk_bf16_f32 %0, %1, %2" : "=v"(r) : "v"(lo), "v"(hi));
  return r;
}
DEV void swap_net(unsigned& a, unsigned& b) {
  asm("v_permlane32_swap_b32 %0, %1" : "+v"(a), "+v"(b));
  asm("v_permlane16_swap_b32 %0, %1" : "+v"(a), "+v"(b));
}
DEV float redmax4(float x) {
  unsigned a = __builtin_bit_cast(unsigned, x), b = a;
  asm("v_permlane16_swap_b32 %0, %1" : "+v"(a), "+v"(b));
  float y = fmaxf(__builtin_bit_cast(float, a), __builtin_bit_cast(float, b));
  unsigned c = __builtin_bit_cast(unsigned, y), d = c;
  asm("v_permlane32_swap_b32 %0, %1" : "+v"(c), "+v"(d));
  return fmaxf(__builtin_bit_cast(float, c), __builtin_bit_cast(float, d));
}
DEV float lanebcast(float v, int srclane) {
  return __builtin_bit_cast(float,
      __builtin_amdgcn_ds_bpermute(srclane * 4, __builtin_bit_cast(int, v)));
}

// ---------------- consolidated converts (+ kgmean) ----------------
__global__ __launch_bounds__(256) void k_cvt_all(
    const float* __restrict__ x, const float* __restrict__ kg,
    const float* __restrict__ Wq, const float* __restrict__ Wk, const float* __restrict__ Wv,
    const float* __restrict__ Wkk, const float* __restrict__ Wkv,
    const float* __restrict__ Wo, const float* __restrict__ Wg,
    ushort_t* __restrict__ xh, ushort_t* __restrict__ kgh,
    ushort_t* __restrict__ WB1, ushort_t* __restrict__ WB2, ushort_t* __restrict__ WB3,
    float* __restrict__ kgm) {
  const int b = blockIdx.x;
  if (b >= 11776) {
    // kgmean: 8 blocks -> 2048 outputs
    const int i = (b - 11776) * 256 + threadIdx.x;
    const int bb = i >> 10, d = i & 1023;
    float s = 0.f;
    #pragma unroll 4
    for (int e = 0; e < 256; e++) s += kg[((size_t)bb * 256 + e) * 1024 + d];
    kgm[i] = s * (1.0f / 256.0f);
    return;
  }
  if (b >= 10752) {
    const int i = (b - 10752) * 256 + threadIdx.x;
    const int r = i >> 8, c = (i & 255) * 4;
    const float4 v = *(const float4*)(Wg + (size_t)r * 2048 + c);
    short4v o;
    o.x = (short)f2bf(v.x); o.y = (short)f2bf(v.y); o.z = (short)f2bf(v.z); o.w = (short)f2bf(v.w);
    *(short4v*)(WB3 + 1048576 + (size_t)r * 1024 + c) = o;
    return;
  }
  const float* src;
  ushort_t* dst;
  int off;
  if (b < 4096)       { src = x;   dst = xh;            off = b; }
  else if (b < 4608)  { src = kg;  dst = kgh;           off = b - 4096; }
  else if (b < 5632)  { src = Wq;  dst = WB1;           off = b - 4608; }
  else if (b < 6656)  { src = Wk;  dst = WB1 + 1048576; off = b - 5632; }
  else if (b < 7680)  { src = Wv;  dst = WB1 + 2097152; off = b - 6656; }
  else if (b < 8704)  { src = Wkk; dst = WB2;           off = b - 7680; }
  else if (b < 9728)  { src = Wkv; dst = WB2 + 1048576; off = b - 8704; }
  else                { src = Wo;  dst = WB3;           off = b - 9728; }
  const int i = off * 1024 + threadIdx.x * 4;
  const float4 v = *(const float4*)(src + i);
  short4v o;
  o.x = (short)f2bf(v.x); o.y = (short)f2bf(v.y); o.z = (short)f2bf(v.z); o.w = (short)f2bf(v.w);
  *(short4v*)(dst + i) = o;
}

__global__ __launch_bounds__(256) void k_g2(const float* __restrict__ kgm, const float* __restrict__ Wg,
                                            const float* __restrict__ bg, float* __restrict__ g2) {
  const int w = threadIdx.x >> 6, l = threadIdx.x & 63;
  const int idx = blockIdx.x * 4 + w;
  const int b = idx >> 10, n = idx & 1023;
  const float* wr = Wg + (size_t)n * 2048 + 1024;
  const float* mb = kgm + b * 1024;
  float s = 0.f;
  #pragma unroll
  for (int j = 0; j < 16; j++) s += mb[j * 64 + l] * wr[j * 64 + l];
  #pragma unroll
  for (int m = 32; m >= 1; m >>= 1) s += __shfl_xor(s, m);
  if (l == 0) g2[idx] = s + bg[n];
}

// ---------------- 128x128x32 GEMM, 3-slot counted-vmcnt pipeline (qkv+kg) ----------------
__global__ __launch_bounds__(256, 3) void k_mm128(
    const ushort_t* __restrict__ A0, const ushort_t* __restrict__ B0,
    const ushort_t* __restrict__ A1, const ushort_t* __restrict__ B1,
    const float* __restrict__ f0, const float* __restrict__ f1, const float* __restrict__ f2,
    const float* __restrict__ f3, const float* __restrict__ f4,
    ushort_t* __restrict__ o0, ushort_t* __restrict__ o1, ushort_t* __restrict__ o2) {
  __shared__ __align__(16) char SHb[49152];   // 3 slots x 16KB; V-epilogue reuses 32KB
  const int tid = threadIdx.x;
  const int w = tid >> 6, l = tid & 63;
  const int wr = w >> 1, wc = w & 1;
  const int fr = l & 15, fg = l >> 4;

  int m0, n0, iskg = 0;
  {
    const int wg = ((int)blockIdx.x & 7) * 104 + ((int)blockIdx.x >> 3);  // 832 = 8*104
    if (wg < 768) { m0 = (wg / 24) * 128; n0 = (wg % 24) * 128; }
    else          { const int k = wg - 768; iskg = 1; m0 = (k >> 4) * 128; n0 = (k & 15) * 128; }
  }
  const ushort_t* A = iskg ? A1 : A0;
  const ushort_t* B = iskg ? B1 : B0;

  int grow[2], gcb[2];
  #pragma unroll
  for (int j = 0; j < 2; j++) {
    const int beta = j * 256 + tid;
    const int rp = beta >> 3;
    const int u = (beta & 7) ^ (rp & 7);
    grow[j] = 2 * rp + (u >> 2);
    gcb[j] = u & 3;
  }
  const char* gA[2];
  const char* gB[2];
  #pragma unroll
  for (int j = 0; j < 2; j++) {
    gA[j] = (const char*)A + (size_t)(m0 + grow[j]) * 2048 + gcb[j] * 16;
    gB[j] = (const char*)B + (size_t)(n0 + grow[j]) * 2048 + gcb[j] * 16;
  }

  auto stage = [&](int s, int kt) {
    char* As = SHb + s * 16384;
    char* Bs = As + 8192;
    const int ko = kt * 64;
    #pragma unroll
    for (int j = 0; j < 2; j++) {
      gl16(gA[j] + ko, As + j * 4096 + tid * 16);
      gl16(gB[j] + ko, Bs + j * 4096 + tid * 16);
    }
  };

  int aoff[4], boff[4];
  #pragma unroll
  for (int i = 0; i < 4; i++) {
    const int rowa = wr * 64 + i * 16 + fr;
    aoff[i] = (rowa >> 1) * 128 + ((((rowa & 1) << 6) | (fg << 4)) ^ (((rowa >> 1) & 7) << 4));
    const int rowb = wc * 64 + i * 16 + fr;
    boff[i] = (rowb >> 1) * 128 + ((((rowb & 1) << 6) | (fg << 4)) ^ (((rowb >> 1) & 7) << 4));
  }

  f32x4 acc[4][4] = {};

  stage(0, 0);
  stage(1, 1);
  int sc = 0, sn2 = 2;
  for (int kt = 0; kt < 32; kt++) {
    if (kt < 31) asm volatile("s_waitcnt vmcnt(4)" ::: "memory");
    else         asm volatile("s_waitcnt vmcnt(0)" ::: "memory");
    __builtin_amdgcn_s_barrier();
    asm volatile("" ::: "memory");
    if (kt < 30) stage(sn2, kt + 2);
    const char* Ab = SHb + sc * 16384;
    const char* Bb = Ab + 8192;
    short8 af[4], bf[4];
    #pragma unroll
    for (int j = 0; j < 4; j++) bf[j] = *(const short8*)(Bb + boff[j]);
    #pragma unroll
    for (int i = 0; i < 4; i++) af[i] = *(const short8*)(Ab + aoff[i]);
    __builtin_amdgcn_s_setprio(1);
    #pragma unroll
    for (int i = 0; i < 4; i++)
      #pragma unroll
      for (int j = 0; j < 4; j++)
        acc[i][j] = mfma_bf16(af[i], bf[j], acc[i][j]);
    __builtin_amdgcn_s_setprio(0);
    sc++; if (sc == 3) sc = 0;
    sn2++; if (sn2 == 3) sn2 = 0;
  }
  __syncthreads();

  const int sec = n0 >> 10;   // main: 0=Q 1=K 2=V ; kg: 0=Kaug-e 1=Vt-e
  const bool isV = (!iskg && sec == 2) || (iskg && sec == 1);

  if (isV) {
    ushort_t* SHs = (ushort_t*)SHb;
    const float* bV = iskg ? f4 : f2;
    const int bidx = iskg ? (m0 >> 8) : (m0 >> 11);
    const int colbase = iskg ? (2048 + (m0 & 255)) : (m0 & 2047);
    #pragma unroll
    for (int i = 0; i < 4; i++) {
      #pragma unroll
      for (int j = 0; j < 4; j++) {
        const int nl = wc * 64 + j * 16 + fr;
        const int ml0 = wr * 64 + i * 16 + fg * 4;
        const float bb = bV[(n0 & 1023) + nl];
        short4v pk;
        #pragma unroll
        for (int r = 0; r < 4; r++) pk[r] = (short)f2bf(acc[i][j][r] + bb);
        *(short4v*)(SHs + nl * 128 + (ml0 ^ ((nl & 7) << 3))) = pk;
      }
    }
    __syncthreads();
    const int row = tid >> 1, half = tid & 1;
    const int h = ((n0 & 1023) >> 6) + (row >> 6);
    const int d = row & 63;
    ushort_t* dst = o2 + ((size_t)(bidx * 16 + h) * 64 + d) * 2304 + colbase + half * 64;
    const ushort_t* srow2 = SHs + row * 128;
    #pragma unroll
    for (int k2 = 0; k2 < 8; k2++) {
      const int me = (half * 64 + k2 * 8) ^ ((row & 7) << 3);
      *(short8*)(dst + k2 * 8) = *(const short8*)(srow2 + me);
    }
    return;
  }

  #pragma unroll
  for (int i = 0; i < 4; i++) {
    #pragma unroll
    for (int j = 0; j < 4; j++) {
      const int nn = (n0 & 1023) + wc * 64 + j * 16 + fr;
      const int h = nn >> 6, d = nn & 63;
      #pragma unroll
      for (int r = 0; r < 4; r++) {
        const int m = m0 + wr * 64 + i * 16 + fg * 4 + r;
        const float v = acc[i][j][r];
        if (iskg) {
          const int b = m >> 8, e = m & 255;
          o1[((size_t)(b * 16 + h) * 2304 + 2048 + e) * 64 + d] = f2bf(v + f3[nn]);
        } else if (sec == 0) {
          const int b = m >> 11, lq = m & 2047;
          o0[((size_t)(b * 16 + h) * 2048 + lq) * 64 + d] = f2bf((v + f0[nn]) * 0.18033688f); // 0.125*log2e
        } else {
          const int b = m >> 11, lq = m & 2047;
          o1[((size_t)(b * 16 + h) * 2304 + lq) * 64 + d] = f2bf(v + f1[nn]);
        }
      }
    }
  }
}

// ---------------- fused output GEMM + gate + final mix ----------------
__global__ __launch_bounds__(256, 2) void k_mmout(
    const ushort_t* __restrict__ Og, const ushort_t* __restrict__ WB3,
    const float* __restrict__ bo, const float* __restrict__ g2v,
    const float* __restrict__ x, float* __restrict__ y) {
  __shared__ __align__(16) char SHb[61440];   // 3 slots x 20KB (A 4K | Bo 8K | Bg 8K)
  const int tid = threadIdx.x;
  const int w = tid >> 6, l = tid & 63;
  const int wr = w >> 1, wc = w & 1;
  const int fr = l & 15, fg = l >> 4;

  const int wg = ((int)blockIdx.x & 7) * 64 + ((int)blockIdx.x >> 3);   // 512 = 8*64
  const int m0 = (wg >> 3) * 64, n0 = (wg & 7) * 128;

  const int rpA = tid >> 3, uA = (tid & 7) ^ (rpA & 7);
  const char* gAp = (const char*)Og + (size_t)(m0 + 2 * rpA + (uA >> 2)) * 2048 + (uA & 3) * 16;
  int grow[2], gcb[2];
  #pragma unroll
  for (int j = 0; j < 2; j++) {
    const int beta = j * 256 + tid;
    const int rp = beta >> 3;
    const int u = (beta & 7) ^ (rp & 7);
    grow[j] = 2 * rp + (u >> 2);
    gcb[j] = u & 3;
  }
  const char* gBo[2];
  const char* gBg[2];
  #pragma unroll
  for (int j = 0; j < 2; j++) {
    gBo[j] = (const char*)WB3 + (size_t)(n0 + grow[j]) * 2048 + gcb[j] * 16;
    gBg[j] = (const char*)(WB3 + 1048576) + (size_t)(n0 + grow[j]) * 2048 + gcb[j] * 16;
  }

  auto stage = [&](int s, int kt) {
    char* As = SHb + s * 20480;
    const int ko = kt * 64;
    gl16(gAp + ko, As + tid * 16);
    #pragma unroll
    for (int j = 0; j < 2; j++) {
      gl16(gBo[j] + ko, As + 4096 + j * 4096 + tid * 16);
      gl16(gBg[j] + ko, As + 12288 + j * 4096 + tid * 16);
    }
  };

  int aoff[2], boff[4];
  #pragma unroll
  for (int i = 0; i < 2; i++) {
    const int rowa = wr * 32 + i * 16 + fr;
    aoff[i] = (rowa >> 1) * 128 + ((((rowa & 1) << 6) | (fg << 4)) ^ (((rowa >> 1) & 7) << 4));
  }
  #pragma unroll
  for (int j = 0; j < 4; j++) {
    const int rowb = wc * 64 + j * 16 + fr;
    boff[j] = (rowb >> 1) * 128 + ((((rowb & 1) << 6) | (fg << 4)) ^ (((rowb >> 1) & 7) << 4));
  }

  f32x4 ao[2][4] = {};
  f32x4 ag[2][4] = {};

  stage(0, 0);
  stage(1, 1);
  int sc = 0, sn2 = 2;
  for (int kt = 0; kt < 32; kt++) {
    if (kt < 31) asm volatile("s_waitcnt vmcnt(5)" ::: "memory");
    else         asm volatile("s_waitcnt vmcnt(0)" ::: "memory");
    __builtin_amdgcn_s_barrier();
    asm volatile("" ::: "memory");
    if (kt < 30) stage(sn2, kt + 2);
    const char* Ab = SHb + sc * 20480;
    short8 af[2], bof[4], bgf[4];
    #pragma unroll
    for (int i = 0; i < 2; i++) af[i] = *(const short8*)(Ab + aoff[i]);
    #pragma unroll
    for (int j = 0; j < 4; j++) {
      bof[j] = *(const short8*)(Ab + 4096 + boff[j]);
      bgf[j] = *(const short8*)(Ab + 12288 + boff[j]);
    }
    __builtin_amdgcn_s_setprio(1);
    #pragma unroll
    for (int i = 0; i < 2; i++)
      #pragma unroll
      for (int j = 0; j < 4; j++) {
        ao[i][j] = mfma_bf16(af[i], bof[j], ao[i][j]);
        ag[i][j] = mfma_bf16(af[i], bgf[j], ag[i][j]);
      }
    __builtin_amdgcn_s_setprio(0);
    sc++; if (sc == 3) sc = 0;
    sn2++; if (sn2 == 3) sn2 = 0;
  }

  const int bidx = m0 >> 11;
  #pragma unroll
  for (int i = 0; i < 2; i++) {
    #pragma unroll
    for (int j = 0; j < 4; j++) {
      const int nn = n0 + wc * 64 + j * 16 + fr;
      const float bb = bo[nn];
      const float gg = g2v[bidx * 1024 + nn];
      #pragma unroll
      for (int r = 0; r < 4; r++) {
        const int m = m0 + wr * 32 + i * 16 + fg * 4 + r;
        const float co = ao[i][j][r] + bb;
        const float cg = ag[i][j][r] + gg;
        const float gate = 1.0f / (1.0f + __builtin_amdgcn_exp2f(cg * -1.4426950408889634f));
        const float xv = x[(size_t)m * 1024 + nn];
        y[(size_t)m * 1024 + nn] = xv + gate * (co - xv);
      }
    }
  }
}

// ---------------- flash attention (QBLK=128, 8 waves, XCD swizzle, z-seeded softmax) ----
__global__ __launch_bounds__(512, 2) void k_attn(
    const ushort_t* __restrict__ Qg, const ushort_t* __restrict__ Kg,
    const ushort_t* __restrict__ Vtg, ushort_t* __restrict__ Og) {
  __shared__ __align__(16) ushort_t Ks[2][64 * 64];
  __shared__ __align__(16) ushort_t Vs[2][64 * 64];
  const int tid = threadIdx.x;
  const int w = tid >> 6, l = tid & 63;
  const int fr = l & 15, fg = l >> 4;

  const int id = blockIdx.x;                               // 0..511
  const int bh = (id & 7) * 4 + ((id >> 3) >> 4);
  const int q0 = ((id >> 3) & 15) * 128 + w * 16;

  short8 qf[2];
  {
    const short* qrow = (const short*)(Qg + ((size_t)bh * 2048 + q0 + fr) * 64);
    qf[0] = *(const short8*)(qrow + fg * 8);
    qf[1] = *(const short8*)(qrow + 32 + fg * 8);
  }

  constexpr short ONE = 0x3F80;  // bf16 1.0
  const short8 ones = {ONE, ONE, ONE, ONE, ONE, ONE, ONE, ONE};

  f32x4 o[4] = {};
  f32x4 lacc = {};
  // shifted-domain online softmax: zs = -mrun seeded into the QK^T accumulator.
  f32x4 zs = {};

  // staging: 512 threads cover each 8KB tile exactly (1 K-gl16 + 1 V-gl16 per thread)
  const int srow = tid >> 3;                                   // 0..63
  const int cS = ((tid & 7) * 16) ^ ((srow & 7) << 4);
  const char* kb0 = (const char*)(Kg + (size_t)bh * 2304 * 64) + (size_t)srow * 128 + cS;
  const char* vb0 = (const char*)(Vtg + (size_t)bh * 64 * 2304) + (size_t)srow * 4608 + cS;
  char* kd0 = (char*)&Ks[0][0] + tid * 16;
  char* vd0 = (char*)&Vs[0][0] + tid * 16;

  auto stage = [&](int nb, int tile) {
    gl16(kb0 + (size_t)tile * 8192, kd0 + nb * 8192);
    gl16(vb0 + tile * 128,          vd0 + nb * 8192);
  };

  stage(0, 0);

  const int rswz = (fr & 7) << 4;

  for (int mt = 0; mt < 36; mt++) {
    __syncthreads();
    if (mt < 35) stage((mt + 1) & 1, mt + 1);

    const char* Kb = (const char*)&Ks[mt & 1][0];
    const char* Vb = (const char*)&Vs[mt & 1][0];

    // swapped QK^T, accumulator pre-seeded with -mrun
    f32x4 s[4];
    #pragma unroll
    for (int t = 0; t < 4; t++) {
      const int rb = (t * 16 + fr) * 128 + fg * 16;
      const short8 k0 = *(const short8*)(Kb + (rb ^ rswz));
      const short8 k1 = *(const short8*)(Kb + ((rb + 64) ^ rswz));
      f32x4 z = zs;
      z = mfma_bf16(k0, qf[0], z);
      z = mfma_bf16(k1, qf[1], z);
      s[t] = z;
    }

    float m = fmaxf(s[0][0], s[0][1]);
    m = fmaxf(fmaxf(m, s[0][2]), s[0][3]);
    m = fmaxf(fmaxf(m, s[1][0]), s[1][1]);
    m = fmaxf(fmaxf(m, s[1][2]), s[1][3]);
    m = fmaxf(fmaxf(m, s[2][0]), s[2][1]);
    m = fmaxf(fmaxf(m, s[2][2]), s[2][3]);
    m = fmaxf(fmaxf(m, s[3][0]), s[3][1]);
    m = fmaxf(fmaxf(m, s[3][2]), s[3][3]);
    const float mx = redmax4(m);
    if (__any(mx > 11.5416f)) {   // cold path: grow the shift, rescale state
      const float d = fmaxf(mx, 0.f);
      const float al = __builtin_amdgcn_exp2f(-d);
      #pragma unroll
      for (int r = 0; r < 4; r++) zs[r] -= d;
      float ab[4];
      #pragma unroll
      for (int r = 0; r < 4; r++) ab[r] = lanebcast(al, fg * 4 + r);
      #pragma unroll
      for (int r = 0; r < 4; r++) {
        lacc[r] *= ab[r];
        #pragma unroll
        for (int dt = 0; dt < 4; dt++) o[dt][r] *= ab[r];
      }
      #pragma unroll
      for (int t = 0; t < 4; t++)
        #pragma unroll
        for (int r = 0; r < 4; r++)
          s[t][r] = __builtin_amdgcn_exp2f(s[t][r] - d);
    } else {                      // hot path: no subtract
      #pragma unroll
      for (int t = 0; t < 4; t++)
        #pragma unroll
        for (int r = 0; r < 4; r++)
          s[t][r] = __builtin_amdgcn_exp2f(s[t][r]);
    }

    #pragma unroll
    for (int c = 0; c < 2; c++) {
      unsigned a0 = cvtpk(s[2 * c][0], s[2 * c][1]);
      unsigned b0 = cvtpk(s[2 * c + 1][0], s[2 * c + 1][1]);
      unsigned a1 = cvtpk(s[2 * c][2], s[2 * c][3]);
      unsigned b1 = cvtpk(s[2 * c + 1][2], s[2 * c + 1][3]);
      swap_net(a0, b0);
      swap_net(a1, b1);
      uintx4 u;
      u.x = a0; u.y = a1; u.z = b0; u.w = b1;
      const short8 pf = __builtin_bit_cast(short8, u);
      lacc = mfma_bf16(pf, ones, lacc);
      #pragma unroll
      for (int dt = 0; dt < 4; dt++) {
        const int vb2 = ((dt * 16 + fr) * 128) + fg * 16 + c * 64;
        const short8 vf = *(const short8*)(Vb + (vb2 ^ rswz));
        o[dt] = mfma_bf16(pf, vf, o[dt]);
      }
    }
  }

  const int b = bh >> 4, h = bh & 15;
  #pragma unroll
  for (int r = 0; r < 4; r++) {
    const float inv = 1.0f / lacc[r];
    const int q = q0 + fg * 4 + r;
    ushort_t* orow = Og + ((size_t)b * 2048 + q) * 1024 + h * 64;
    #pragma unroll
    for (int dt = 0; dt < 4; dt++) orow[dt * 16 + fr] = f2bf(o[dt][r] * inv);
  }
}

extern "C" void kernel_launch(void* const* d_in, const int* in_sizes, int n_in,
                              void* d_out, int out_size, void* d_ws, size_t ws_size,
                              hipStream_t stream) {
  (void)in_sizes; (void)n_in; (void)out_size; (void)ws_size;
  const float* x   = (const float*)d_in[0];
  const float* kg  = (const float*)d_in[1];
  const float* Wq  = (const float*)d_in[2];
  const float* bq  = (const float*)d_in[3];
  const float* Wk  = (const float*)d_in[4];
  const float* bk  = (const float*)d_in[5];
  const float* Wv  = (const float*)d_in[6];
  const float* bv  = (const float*)d_in[7];
  const float* Wkk = (const float*)d_in[8];
  const float* bkk = (const float*)d_in[9];
  const float* Wkv = (const float*)d_in[10];
  const float* bkv = (const float*)d_in[11];
  const float* Wo  = (const float*)d_in[12];
  const float* bo  = (const float*)d_in[13];
  const float* Wg  = (const float*)d_in[14];
  const float* bg  = (const float*)d_in[15];
  float* y = (float*)d_out;

  char* ws = (char*)d_ws;
  size_t off = 0;
  auto take = [&](size_t bytes) {
    char* p = ws + off;
    off += (bytes + 255) & ~(size_t)255;
    return p;
  };
  ushort_t* xh   = (ushort_t*)take((size_t)4096 * 1024 * 2);
  ushort_t* kgh  = (ushort_t*)take((size_t)512 * 1024 * 2);
  ushort_t* WB1  = (ushort_t*)take((size_t)3072 * 1024 * 2);
  ushort_t* WB2  = (ushort_t*)take((size_t)2048 * 1024 * 2);
  ushort_t* WB3  = (ushort_t*)take((size_t)2048 * 1024 * 2);
  ushort_t* Qg   = (ushort_t*)take((size_t)32 * 2048 * 64 * 2);
  ushort_t* Kaug = (ushort_t*)take((size_t)32 * 2304 * 64 * 2);
  ushort_t* Vt   = (ushort_t*)take((size_t)32 * 2304 * 64 * 2);
  ushort_t* Og   = (ushort_t*)take((size_t)4096 * 1024 * 2);
  float* kgm     = (float*)take(2048 * 4);
  float* g2      = (float*)take(2048 * 4);

  k_cvt_all<<<11784, 256, 0, stream>>>(x, kg, Wq, Wk, Wv, Wkk, Wkv, Wo, Wg,
                                       xh, kgh, WB1, WB2, WB3, kgm);
  k_g2<<<512, 256, 0, stream>>>(kgm, Wg, bg, g2);

  k_mm128<<<832, 256, 0, stream>>>(xh, WB1, kgh, WB2,
                                   bq, bk, bv, bkk, bkv, Qg, Kaug, Vt);
  k_attn<<<512, 512, 0, stream>>>(Qg, Kaug, Vt, Og);
  k_mmout<<<512, 256, 0, stream>>>(Og, WB3, bo, g2, x, y);
}